// Round 1
// baseline (560.871 us; speedup 1.0000x reference)
//
#include <hip/hip_runtime.h>

// ---------------------------------------------------------------------------
// MultiHeadSelfAttentionWithRoPE: B=4, S=2048, D_MODEL=1024, H=16, D_K=64
// Pipeline: cvt->bf16 | QKV GEMMs (mfma bf16) | RoPE | causal flash attn | out GEMM
// ---------------------------------------------------------------------------

typedef float f32x4 __attribute__((ext_vector_type(4)));
typedef __bf16 bf16x8 __attribute__((ext_vector_type(8)));
typedef __bf16 bf16x4 __attribute__((ext_vector_type(4)));

#define MFMA16(a, b, c) __builtin_amdgcn_mfma_f32_16x16x32_bf16((a), (b), (c), 0, 0, 0)

#define GL16(gp, lp)                                                        \
  __builtin_amdgcn_global_load_lds(                                         \
      (const __attribute__((address_space(1))) void*)(gp),                  \
      (__attribute__((address_space(3))) void*)(lp), 16, 0, 0)

// ------------------------------- cvt f32 -> bf16 ---------------------------
__global__ void cvt_kernel(const float* __restrict__ src, __bf16* __restrict__ dst, int n4) {
  int i = blockIdx.x * blockDim.x + threadIdx.x;
  if (i < n4) {
    float4 v = ((const float4*)src)[i];
    bf16x4 o;
    o[0] = (__bf16)v.x; o[1] = (__bf16)v.y; o[2] = (__bf16)v.z; o[3] = (__bf16)v.w;
    ((bf16x4*)dst)[i] = o;
  }
}

// ------------------------------- RoPE table --------------------------------
__global__ void rope_table(float* __restrict__ ct, float* __restrict__ st) {
  int i = blockIdx.x * 256 + threadIdx.x;  // 65536 = 2048 pos * 32 freq
  int pos = i >> 5, f = i & 31;
  float inv = powf(10000.0f, -(float)f * (1.0f / 32.0f));
  float a = (float)pos * inv;
  ct[i] = cosf(a);
  st[i] = sinf(a);
}

// ------------------------------- RoPE apply (in-place) ---------------------
__global__ void rope_apply(__bf16* __restrict__ buf, const int* __restrict__ tpos,
                           const float* __restrict__ ct, const float* __restrict__ st) {
  int tid = blockIdx.x * 256 + threadIdx.x;  // 4*16*2048*32 = 4194304
  int i = tid & 31;
  int s = (tid >> 5) & 2047;
  int b = tid >> 20;
  int pos = tpos[(b << 11) + s];
  size_t base = (size_t)(tid >> 5) * 64;  // ((b*16+h)*2048+s)*64
  float c = ct[(pos << 5) + i];
  float sn = st[(pos << 5) + i];
  float q1 = (float)buf[base + i];
  float q2 = (float)buf[base + 32 + i];
  buf[base + i] = (__bf16)(q1 * c - q2 * sn);
  buf[base + 32 + i] = (__bf16)(q2 * c + q1 * sn);
}

// ------------------------------- GEMM: C = A(MxK) * B(NxK)^T ----------------
// MODE 0: out bf16 scattered to (B=4, H=16, S=2048, DK=64)
// MODE 1: out f32 row-major MxN
template <int MODE>
__global__ __launch_bounds__(256) void gemm_bt(const __bf16* __restrict__ A,
                                               const __bf16* __restrict__ Bw,
                                               void* __restrict__ Cout, int K) {
  __shared__ __align__(16) __bf16 As[128 * 32];
  __shared__ __align__(16) __bf16 Bs[128 * 32];
  const int t = threadIdx.x;
  const int w = t >> 6, l = t & 63;
  const int lr = l & 15, lg = l >> 4;
  const int wr = w >> 1, wc = w & 1;
  const int bm = blockIdx.x, bn = blockIdx.y;

  f32x4 acc[4][4] = {};

  const __bf16* ag = A + (size_t)(bm * 128 + (t >> 2)) * K + (t & 3) * 8;
  const __bf16* bg = Bw + (size_t)(bn * 128 + (t >> 2)) * K + (t & 3) * 8;
  __bf16* asl = As + w * 512;  // wave-uniform LDS base (bytes: w*1024)
  __bf16* bsl = Bs + w * 512;

  for (int kt = 0; kt < K; kt += 32) {
    GL16(ag + kt, asl);
    GL16(ag + kt + (size_t)64 * K, asl + 2048);
    GL16(bg + kt, bsl);
    GL16(bg + kt + (size_t)64 * K, bsl + 2048);
    __syncthreads();
    bf16x8 af[4], bf[4];
#pragma unroll
    for (int i = 0; i < 4; ++i) {
      af[i] = *(const bf16x8*)&As[(wr * 64 + i * 16 + lr) * 32 + lg * 8];
      bf[i] = *(const bf16x8*)&Bs[(wc * 64 + i * 16 + lr) * 32 + lg * 8];
    }
#pragma unroll
    for (int i = 0; i < 4; ++i)
#pragma unroll
      for (int j = 0; j < 4; ++j) acc[i][j] = MFMA16(af[i], bf[j], acc[i][j]);
    __syncthreads();
  }

#pragma unroll
  for (int i = 0; i < 4; ++i)
#pragma unroll
    for (int j = 0; j < 4; ++j)
#pragma unroll
      for (int e = 0; e < 4; ++e) {
        int grow = bm * 128 + wr * 64 + i * 16 + lg * 4 + e;
        int gcol = bn * 128 + wc * 64 + j * 16 + lr;
        float v = acc[i][j][e];
        if (MODE == 0) {
          int b = grow >> 11, s = grow & 2047;
          int h = gcol >> 6, d = gcol & 63;
          ((__bf16*)Cout)[(((size_t)(b * 16 + h)) * 2048 + s) * 64 + d] = (__bf16)v;
        } else {
          ((float*)Cout)[(size_t)grow * 1024 + gcol] = v;
        }
      }
}

// ------------------------------- causal flash attention --------------------
// grid: (S/64, B*H); 256 threads = 4 waves, each wave owns 16 Q rows.
__global__ __launch_bounds__(256) void attn_fwd(const __bf16* __restrict__ Q,
                                                const __bf16* __restrict__ Kb,
                                                const __bf16* __restrict__ Vb,
                                                __bf16* __restrict__ O) {
  __shared__ __align__(16) __bf16 Ks[32][72];   // padded: 2-way bank conflicts only
  __shared__ __align__(16) __bf16 VT[64][40];   // V transposed: VT[d][key]
  __shared__ __align__(16) __bf16 Ps[4][16][40];  // per-wave P transpose buffer
  const int t = threadIdx.x, w = t >> 6, l = t & 63;
  const int lr = l & 15, lg = l >> 4;
  const int qb = blockIdx.x, bh = blockIdx.y;
  const int q0 = qb * 64;
  const size_t base = (size_t)bh * (2048 * 64);

  // Q fragments in registers (A-operand rows = l&15)
  bf16x8 qf0 = *(const bf16x8*)&Q[base + (size_t)(q0 + w * 16 + lr) * 64 + lg * 8];
  bf16x8 qf1 = *(const bf16x8*)&Q[base + (size_t)(q0 + w * 16 + lr) * 64 + 32 + lg * 8];

  float mrun[4], lrun[4];
  f32x4 oa[4] = {};
#pragma unroll
  for (int j = 0; j < 4; ++j) { mrun[j] = -1e30f; lrun[j] = 0.0f; }

  const int nkb = (q0 >> 5) + 2;  // causal: keys < q0+64
  for (int kb = 0; kb < nkb; ++kb) {
    const int k0 = kb * 32;
    {  // stage K tile + V tile (transposed)
      const int r = t >> 3, c = (t & 7) * 8;
      bf16x8 kv = *(const bf16x8*)&Kb[base + (size_t)(k0 + r) * 64 + c];
      *(bf16x8*)&Ks[r][c] = kv;
      bf16x8 vv = *(const bf16x8*)&Vb[base + (size_t)(k0 + r) * 64 + c];
#pragma unroll
      for (int e = 0; e < 8; ++e) VT[c + e][r] = vv[e];
    }
    __syncthreads();

    // scores: S = Q K^T   (C layout: row=(l>>4)*4+j (query), col=l&15 (key))
    f32x4 sc[2];
#pragma unroll
    for (int sk = 0; sk < 2; ++sk) {
      bf16x8 kf0 = *(const bf16x8*)&Ks[sk * 16 + lr][lg * 8];
      bf16x8 kf1 = *(const bf16x8*)&Ks[sk * 16 + lr][32 + lg * 8];
      f32x4 z = {0.0f, 0.0f, 0.0f, 0.0f};
      z = MFMA16(qf0, kf0, z);
      z = MFMA16(qf1, kf1, z);
      sc[sk] = z;
    }
    // scale + causal mask
#pragma unroll
    for (int sk = 0; sk < 2; ++sk)
#pragma unroll
      for (int j = 0; j < 4; ++j) {
        int kg = k0 + sk * 16 + lr;
        int qg = q0 + w * 16 + lg * 4 + j;
        float s = sc[sk][j] * 0.125f;
        sc[sk][j] = (kg > qg) ? -1e30f : s;
      }
    // online softmax (16-lane row groups)
    float mx[4];
#pragma unroll
    for (int j = 0; j < 4; ++j) mx[j] = fmaxf(sc[0][j], sc[1][j]);
#pragma unroll
    for (int d = 1; d < 16; d <<= 1)
#pragma unroll
      for (int j = 0; j < 4; ++j) mx[j] = fmaxf(mx[j], __shfl_xor(mx[j], d));
    float corr[4], rs[4];
#pragma unroll
    for (int j = 0; j < 4; ++j) {
      float nm = fmaxf(mrun[j], mx[j]);
      corr[j] = __expf(mrun[j] - nm);
      mrun[j] = nm;
      rs[j] = 0.0f;
    }
#pragma unroll
    for (int sk = 0; sk < 2; ++sk)
#pragma unroll
      for (int j = 0; j < 4; ++j) {
        float p = __expf(sc[sk][j] - mrun[j]);
        sc[sk][j] = p;
        rs[j] += p;
      }
#pragma unroll
    for (int d = 1; d < 16; d <<= 1)
#pragma unroll
      for (int j = 0; j < 4; ++j) rs[j] += __shfl_xor(rs[j], d);
#pragma unroll
    for (int j = 0; j < 4; ++j) lrun[j] = lrun[j] * corr[j] + rs[j];
#pragma unroll
    for (int nf = 0; nf < 4; ++nf)
#pragma unroll
      for (int j = 0; j < 4; ++j) oa[nf][j] *= corr[j];

    // P -> per-wave LDS -> A-fragment form (row=query=l&15, k=key)
#pragma unroll
    for (int sk = 0; sk < 2; ++sk)
#pragma unroll
      for (int j = 0; j < 4; ++j)
        Ps[w][lg * 4 + j][sk * 16 + lr] = (__bf16)sc[sk][j];
    bf16x8 pf = *(const bf16x8*)&Ps[w][lr][lg * 8];

    // PV: oa[nf] += P(16x32) * V(32x16-per-nf)
#pragma unroll
    for (int nf = 0; nf < 4; ++nf) {
      bf16x8 vf = *(const bf16x8*)&VT[nf * 16 + lr][lg * 8];
      oa[nf] = MFMA16(pf, vf, oa[nf]);
    }
    __syncthreads();
  }

  const int b = bh >> 4, h = bh & 15;
#pragma unroll
  for (int nf = 0; nf < 4; ++nf)
#pragma unroll
    for (int j = 0; j < 4; ++j) {
      int qg = q0 + w * 16 + lg * 4 + j;
      int d = nf * 16 + lr;
      float v = oa[nf][j] / lrun[j];
      O[((size_t)(b * 2048 + qg)) * 1024 + h * 64 + d] = (__bf16)v;
    }
}

// ---------------------------------------------------------------------------
extern "C" void kernel_launch(void* const* d_in, const int* in_sizes, int n_in,
                              void* d_out, int out_size, void* d_ws, size_t ws_size,
                              hipStream_t stream) {
  const float* x = (const float*)d_in[0];
  const float* wq = (const float*)d_in[1];
  const float* wk = (const float*)d_in[2];
  const float* wv = (const float*)d_in[3];
  const float* wo = (const float*)d_in[4];
  const int* tpos = (const int*)d_in[5];
  float* out = (float*)d_out;

  // workspace layout (bytes, all offsets 256-aligned)
  const size_t SZ_X = 8192u * 1024u * 2u;   // 16777216
  const size_t SZ_W = 1024u * 1024u * 2u;   // 2097152
  const size_t SZ_T = 2048u * 32u * 4u;     // 262144
  const size_t NEED = SZ_X * 4 + SZ_W * 4 + SZ_T * 2;  // ~76 MB (AO aliases xb)
  if (ws_size < NEED) return;  // fail loudly via wrong output

  char* p = (char*)d_ws;
  __bf16* xb  = (__bf16*)p; p += SZ_X;   // also reused as attention output (AO)
  __bf16* wqb = (__bf16*)p; p += SZ_W;
  __bf16* wkb = (__bf16*)p; p += SZ_W;
  __bf16* wvb = (__bf16*)p; p += SZ_W;
  __bf16* wob = (__bf16*)p; p += SZ_W;
  __bf16* Qb  = (__bf16*)p; p += SZ_X;
  __bf16* Kbf = (__bf16*)p; p += SZ_X;
  __bf16* Vbf = (__bf16*)p; p += SZ_X;
  float* ct = (float*)p; p += SZ_T;
  float* st = (float*)p; p += SZ_T;
  __bf16* AOb = xb;  // x no longer needed after QKV GEMMs

  cvt_kernel<<<8192, 256, 0, stream>>>(x, xb, 2097152);
  cvt_kernel<<<1024, 256, 0, stream>>>(wq, wqb, 262144);
  cvt_kernel<<<1024, 256, 0, stream>>>(wk, wkb, 262144);
  cvt_kernel<<<1024, 256, 0, stream>>>(wv, wvb, 262144);
  cvt_kernel<<<1024, 256, 0, stream>>>(wo, wob, 262144);
  rope_table<<<256, 256, 0, stream>>>(ct, st);

  gemm_bt<0><<<dim3(64, 8), 256, 0, stream>>>(xb, wqb, (void*)Qb, 1024);
  gemm_bt<0><<<dim3(64, 8), 256, 0, stream>>>(xb, wkb, (void*)Kbf, 1024);
  gemm_bt<0><<<dim3(64, 8), 256, 0, stream>>>(xb, wvb, (void*)Vbf, 1024);

  rope_apply<<<16384, 256, 0, stream>>>(Qb, tpos, ct, st);
  rope_apply<<<16384, 256, 0, stream>>>(Kbf, tpos, ct, st);

  attn_fwd<<<dim3(32, 64), 256, 0, stream>>>(Qb, Kbf, Vbf, AOb);

  gemm_bt<1><<<dim3(64, 8), 256, 0, stream>>>(AOb, wob, (void*)out, 1024);
}

// Round 2
// 312.760 us; speedup vs baseline: 1.7933x; 1.7933x over previous
//
#include <hip/hip_runtime.h>

// ---------------------------------------------------------------------------
// MultiHeadSelfAttentionWithRoPE: B=4, S=2048, D_MODEL=1024, H=16, D_K=64
// cvt->bf16 | QKV GEMMs (mfma bf16) | RoPE | swapped-QK^T 32x32 flash attn | out GEMM
// ---------------------------------------------------------------------------

typedef float f32x4 __attribute__((ext_vector_type(4)));
typedef float f32x16 __attribute__((ext_vector_type(16)));
typedef __bf16 bf16x8 __attribute__((ext_vector_type(8)));
typedef __bf16 bf16x4 __attribute__((ext_vector_type(4)));
typedef unsigned int u32;

#define MFMA16(a, b, c) __builtin_amdgcn_mfma_f32_16x16x32_bf16((a), (b), (c), 0, 0, 0)
#define MFMA32(a, b, c) __builtin_amdgcn_mfma_f32_32x32x16_bf16((a), (b), (c), 0, 0, 0)

#define GL16(gp, lp)                                                        \
  __builtin_amdgcn_global_load_lds(                                         \
      (const __attribute__((address_space(1))) void*)(gp),                  \
      (__attribute__((address_space(3))) void*)(lp), 16, 0, 0)

// ------------------------------- cvt f32 -> bf16 ---------------------------
__global__ void cvt_kernel(const float* __restrict__ src, __bf16* __restrict__ dst, int n4) {
  int i = blockIdx.x * blockDim.x + threadIdx.x;
  if (i < n4) {
    float4 v = ((const float4*)src)[i];
    bf16x4 o;
    o[0] = (__bf16)v.x; o[1] = (__bf16)v.y; o[2] = (__bf16)v.z; o[3] = (__bf16)v.w;
    ((bf16x4*)dst)[i] = o;
  }
}

// ------------------------------- RoPE table --------------------------------
__global__ void rope_table(float* __restrict__ ct, float* __restrict__ st) {
  int i = blockIdx.x * 256 + threadIdx.x;  // 65536 = 2048 pos * 32 freq
  int pos = i >> 5, f = i & 31;
  float inv = powf(10000.0f, -(float)f * (1.0f / 32.0f));
  float a = (float)pos * inv;
  ct[i] = cosf(a);
  st[i] = sinf(a);
}

// ------------------------------- RoPE apply (in-place) ---------------------
__global__ void rope_apply(__bf16* __restrict__ buf, const int* __restrict__ tpos,
                           const float* __restrict__ ct, const float* __restrict__ st) {
  int tid = blockIdx.x * 256 + threadIdx.x;  // 4*16*2048*32 = 4194304
  int i = tid & 31;
  int s = (tid >> 5) & 2047;
  int b = tid >> 20;
  int pos = tpos[(b << 11) + s];
  size_t base = (size_t)(tid >> 5) * 64;  // ((b*16+h)*2048+s)*64
  float c = ct[(pos << 5) + i];
  float sn = st[(pos << 5) + i];
  float q1 = (float)buf[base + i];
  float q2 = (float)buf[base + 32 + i];
  buf[base + i] = (__bf16)(q1 * c - q2 * sn);
  buf[base + 32 + i] = (__bf16)(q2 * c + q1 * sn);
}

// ------------------------------- GEMM: C = A(MxK) * B(NxK)^T ----------------
template <int MODE>
__global__ __launch_bounds__(256) void gemm_bt(const __bf16* __restrict__ A,
                                               const __bf16* __restrict__ Bw,
                                               void* __restrict__ Cout, int K) {
  __shared__ __align__(16) __bf16 As[128 * 32];
  __shared__ __align__(16) __bf16 Bs[128 * 32];
  const int t = threadIdx.x;
  const int w = t >> 6, l = t & 63;
  const int lr = l & 15, lg = l >> 4;
  const int wr = w >> 1, wc = w & 1;
  const int bm = blockIdx.x, bn = blockIdx.y;

  f32x4 acc[4][4] = {};

  const __bf16* ag = A + (size_t)(bm * 128 + (t >> 2)) * K + (t & 3) * 8;
  const __bf16* bg = Bw + (size_t)(bn * 128 + (t >> 2)) * K + (t & 3) * 8;
  __bf16* asl = As + w * 512;
  __bf16* bsl = Bs + w * 512;

  for (int kt = 0; kt < K; kt += 32) {
    GL16(ag + kt, asl);
    GL16(ag + kt + (size_t)64 * K, asl + 2048);
    GL16(bg + kt, bsl);
    GL16(bg + kt + (size_t)64 * K, bsl + 2048);
    __syncthreads();
    bf16x8 af[4], bf[4];
#pragma unroll
    for (int i = 0; i < 4; ++i) {
      af[i] = *(const bf16x8*)&As[(wr * 64 + i * 16 + lr) * 32 + lg * 8];
      bf[i] = *(const bf16x8*)&Bs[(wc * 64 + i * 16 + lr) * 32 + lg * 8];
    }
#pragma unroll
    for (int i = 0; i < 4; ++i)
#pragma unroll
      for (int j = 0; j < 4; ++j) acc[i][j] = MFMA16(af[i], bf[j], acc[i][j]);
    __syncthreads();
  }

#pragma unroll
  for (int i = 0; i < 4; ++i)
#pragma unroll
    for (int j = 0; j < 4; ++j)
#pragma unroll
      for (int e = 0; e < 4; ++e) {
        int grow = bm * 128 + wr * 64 + i * 16 + lg * 4 + e;
        int gcol = bn * 128 + wc * 64 + j * 16 + lr;
        float v = acc[i][j][e];
        if (MODE == 0) {
          int b = grow >> 11, s = grow & 2047;
          int h = gcol >> 6, d = gcol & 63;
          ((__bf16*)Cout)[(((size_t)(b * 16 + h)) * 2048 + s) * 64 + d] = (__bf16)v;
        } else {
          ((float*)Cout)[(size_t)grow * 1024 + gcol] = v;
        }
      }
}

// ------------------------- swapped-QK^T flash attention --------------------
// grid: (16, 64) = (qb, b*16+h). 256 threads = 4 warps, each warp owns 32 q.
// Per KV tile (64 keys): S^T = mfma32(K,Q) -> lane-local P row (q = lane&31),
// in-register softmax, P repack via pack+shfl_xor(32), O^T = mfma32(V^T, P).

static __device__ __forceinline__ u32 pk2(float a, float b) {
  union { __bf16 h[2]; u32 w; } u;
  u.h[0] = (__bf16)a; u.h[1] = (__bf16)b;
  return u.w;
}

// Build PV B-fragment covering 16 k values from 8 per-lane P regs (pair lane
// holds the interleaved other half); exchange via shfl_xor(32).
#define PACK_FRAG(SRC, OFF, OUT)                                            \
  {                                                                         \
    u32 c01 = pk2(SRC[(OFF) + 0], SRC[(OFF) + 1]);                          \
    u32 c23 = pk2(SRC[(OFF) + 2], SRC[(OFF) + 3]);                          \
    u32 c45 = pk2(SRC[(OFF) + 4], SRC[(OFF) + 5]);                          \
    u32 c67 = pk2(SRC[(OFF) + 6], SRC[(OFF) + 7]);                          \
    u32 x1_ = (u32)__shfl_xor((int)(hi ? c01 : c45), 32);                   \
    u32 x2_ = (u32)__shfl_xor((int)(hi ? c23 : c67), 32);                   \
    union { u32 w[4]; bf16x8 v; } fu_;                                      \
    fu_.w[0] = hi ? x1_ : c01;                                              \
    fu_.w[1] = hi ? x2_ : c23;                                              \
    fu_.w[2] = hi ? c45 : x1_;                                              \
    fu_.w[3] = hi ? c67 : x2_;                                              \
    OUT = fu_.v;                                                            \
  }

__global__ __launch_bounds__(256) void attn_fwd(const __bf16* __restrict__ Q,
                                                const __bf16* __restrict__ Kb,
                                                const __bf16* __restrict__ Vb,
                                                __bf16* __restrict__ O) {
  // stride 72 bf16 = 144B: ds_read_b128 slot = (row + 2*col16)%8 -> 8 lanes/slot
  __shared__ __align__(16) __bf16 Ks[64][72];
  __shared__ __align__(16) __bf16 VT[64][72];
  const int t = threadIdx.x, w = t >> 6, l = t & 63;
  const int lq = l & 31, hi = l >> 5;
  const int qb = 15 - blockIdx.x;  // heavy blocks dispatch first
  const int bh = blockIdx.y;
  const int q0w = qb * 128 + w * 32;
  const int qrow = q0w + lq;
  const size_t base = (size_t)bh * (2048 * 64);

  // Q B-fragments (col=q=lane&31, kdim d = ds*16 + hi*8 + e), 1/8 folded in
  bf16x8 qf[4];
#pragma unroll
  for (int ds = 0; ds < 4; ++ds) {
    bf16x8 raw = *(const bf16x8*)&Q[base + (size_t)qrow * 64 + ds * 16 + hi * 8];
    bf16x8 sc;
#pragma unroll
    for (int e = 0; e < 8; ++e) sc[e] = (__bf16)((float)raw[e] * 0.125f);
    qf[ds] = sc;
  }

  f32x16 ot0 = {}, ot1 = {};  // O^T: rows d (reg-mapped), col q = lane&31
  float mrun = -1e30f, lrun = 0.0f;

  const int vd = t & 63, vkg = t >> 6;       // V gather: lane = d, warp = k-group
  const int kr = t >> 2, kc = (t & 3) * 16;  // K stage: row, col

  const int nkt = qb * 2 + 2;
  for (int kt = 0; kt < nkt; ++kt) {
    const int k0 = kt * 64;
    {  // ---- stage K (row-major) + V (transposed, coalesced gather)
      const __bf16* kgp = &Kb[base + (size_t)(k0 + kr) * 64 + kc];
      *(bf16x8*)&Ks[kr][kc] = *(const bf16x8*)kgp;
      *(bf16x8*)&Ks[kr][kc + 8] = *(const bf16x8*)(kgp + 8);
      bf16x8 v0, v1;
#pragma unroll
      for (int kk = 0; kk < 8; ++kk)
        v0[kk] = Vb[base + (size_t)(k0 + vkg * 16 + kk) * 64 + vd];
#pragma unroll
      for (int kk = 0; kk < 8; ++kk)
        v1[kk] = Vb[base + (size_t)(k0 + vkg * 16 + 8 + kk) * 64 + vd];
      *(bf16x8*)&VT[vd][vkg * 16] = v0;
      *(bf16x8*)&VT[vd][vkg * 16 + 8] = v1;
    }
    __syncthreads();

    if (k0 <= q0w + 31) {  // warp-uniform: tile not fully masked
      // S^T tiles: rows k (reg-mapped), col q = lane&31
      f32x16 st0 = {}, st1 = {};
#pragma unroll
      for (int ds = 0; ds < 4; ++ds) {
        bf16x8 kf = *(const bf16x8*)&Ks[lq][ds * 16 + hi * 8];
        st0 = MFMA32(kf, qf[ds], st0);
      }
#pragma unroll
      for (int ds = 0; ds < 4; ++ds) {
        bf16x8 kf = *(const bf16x8*)&Ks[32 + lq][ds * 16 + hi * 8];
        st1 = MFMA32(kf, qf[ds], st1);
      }

      float pmax = -1e30f;
      const bool full = (k0 + 63 <= q0w);
      if (full) {
#pragma unroll
        for (int r = 0; r < 16; ++r) pmax = fmaxf(pmax, fmaxf(st0[r], st1[r]));
      } else {
#pragma unroll
        for (int r = 0; r < 16; ++r) {
          int kl = k0 + (r & 3) + 8 * (r >> 2) + 4 * hi;  // k of reg r (st0)
          float s0 = (kl > qrow) ? -1e30f : st0[r];
          float s1 = (kl + 32 > qrow) ? -1e30f : st1[r];
          st0[r] = s0;
          st1[r] = s1;
          pmax = fmaxf(pmax, fmaxf(s0, s1));
        }
      }
      pmax = fmaxf(pmax, __shfl_xor(pmax, 32));  // pair lane holds other half-row

      if (!__all(pmax <= mrun)) {  // defer-max: skip rescale when no growth
        float nm = fmaxf(mrun, pmax);
        float corr = __expf(mrun - nm);
        mrun = nm;
        lrun *= corr;
#pragma unroll
        for (int r = 0; r < 16; ++r) { ot0[r] *= corr; ot1[r] *= corr; }
      }

      float rs = 0.0f;
#pragma unroll
      for (int r = 0; r < 16; ++r) {
        float e0 = __expf(st0[r] - mrun);
        float e1 = __expf(st1[r] - mrun);
        st0[r] = e0; st1[r] = e1;
        rs += e0 + e1;
      }
      rs += __shfl_xor(rs, 32);
      lrun += rs;

      bf16x8 pa[4];  // PV B-frags: k slices 0..3 (16 k each)
      PACK_FRAG(st0, 0, pa[0])
      PACK_FRAG(st0, 8, pa[1])
      PACK_FRAG(st1, 0, pa[2])
      PACK_FRAG(st1, 8, pa[3])

#pragma unroll
      for (int fi = 0; fi < 4; ++fi) {
        bf16x8 vf = *(const bf16x8*)&VT[lq][fi * 16 + hi * 8];
        ot0 = MFMA32(vf, pa[fi], ot0);
      }
#pragma unroll
      for (int fi = 0; fi < 4; ++fi) {
        bf16x8 vf = *(const bf16x8*)&VT[32 + lq][fi * 16 + hi * 8];
        ot1 = MFMA32(vf, pa[fi], ot1);
      }
    }
    __syncthreads();
  }

  // epilogue: O^T reg r -> d = dtile*32 + (r&3) + 8*(r>>2) + 4*hi, q = lane&31
  const int b = bh >> 4, h = bh & 15;
  float inv = 1.0f / lrun;
  __bf16* orow = O + ((size_t)(b * 2048 + qrow)) * 1024 + h * 64;
#pragma unroll
  for (int rq = 0; rq < 4; ++rq) {
    bf16x4 v0, v1;
#pragma unroll
    for (int e = 0; e < 4; ++e) {
      v0[e] = (__bf16)(ot0[rq * 4 + e] * inv);
      v1[e] = (__bf16)(ot1[rq * 4 + e] * inv);
    }
    *(bf16x4*)&orow[8 * rq + 4 * hi] = v0;
    *(bf16x4*)&orow[32 + 8 * rq + 4 * hi] = v1;
  }
}

// ---------------------------------------------------------------------------
extern "C" void kernel_launch(void* const* d_in, const int* in_sizes, int n_in,
                              void* d_out, int out_size, void* d_ws, size_t ws_size,
                              hipStream_t stream) {
  const float* x = (const float*)d_in[0];
  const float* wq = (const float*)d_in[1];
  const float* wk = (const float*)d_in[2];
  const float* wv = (const float*)d_in[3];
  const float* wo = (const float*)d_in[4];
  const int* tpos = (const int*)d_in[5];
  float* out = (float*)d_out;

  const size_t SZ_X = 8192u * 1024u * 2u;
  const size_t SZ_W = 1024u * 1024u * 2u;
  const size_t SZ_T = 2048u * 32u * 4u;
  const size_t NEED = SZ_X * 4 + SZ_W * 4 + SZ_T * 2;
  if (ws_size < NEED) return;

  char* p = (char*)d_ws;
  __bf16* xb  = (__bf16*)p; p += SZ_X;   // reused as attention output (AO)
  __bf16* wqb = (__bf16*)p; p += SZ_W;
  __bf16* wkb = (__bf16*)p; p += SZ_W;
  __bf16* wvb = (__bf16*)p; p += SZ_W;
  __bf16* wob = (__bf16*)p; p += SZ_W;
  __bf16* Qb  = (__bf16*)p; p += SZ_X;
  __bf16* Kbf = (__bf16*)p; p += SZ_X;
  __bf16* Vbf = (__bf16*)p; p += SZ_X;
  float* ct = (float*)p; p += SZ_T;
  float* st = (float*)p; p += SZ_T;
  __bf16* AOb = xb;

  cvt_kernel<<<8192, 256, 0, stream>>>(x, xb, 2097152);
  cvt_kernel<<<1024, 256, 0, stream>>>(wq, wqb, 262144);
  cvt_kernel<<<1024, 256, 0, stream>>>(wk, wkb, 262144);
  cvt_kernel<<<1024, 256, 0, stream>>>(wv, wvb, 262144);
  cvt_kernel<<<1024, 256, 0, stream>>>(wo, wob, 262144);
  rope_table<<<256, 256, 0, stream>>>(ct, st);

  gemm_bt<0><<<dim3(64, 8), 256, 0, stream>>>(xb, wqb, (void*)Qb, 1024);
  gemm_bt<0><<<dim3(64, 8), 256, 0, stream>>>(xb, wkb, (void*)Kbf, 1024);
  gemm_bt<0><<<dim3(64, 8), 256, 0, stream>>>(xb, wvb, (void*)Vbf, 1024);

  rope_apply<<<16384, 256, 0, stream>>>(Qb, tpos, ct, st);
  rope_apply<<<16384, 256, 0, stream>>>(Kbf, tpos, ct, st);

  attn_fwd<<<dim3(16, 64), 256, 0, stream>>>(Qb, Kbf, Vbf, AOb);

  gemm_bt<1><<<dim3(64, 8), 256, 0, stream>>>(AOb, wob, (void*)out, 1024);
}

// Round 3
// 278.833 us; speedup vs baseline: 2.0115x; 1.1217x over previous
//
#include <hip/hip_runtime.h>

// ---------------------------------------------------------------------------
// MultiHeadSelfAttentionWithRoPE: B=4, S=2048, D_MODEL=1024, H=16, D_K=64
// cvt->bf16 | QKV GEMMs (V written transposed) | RoPE | dbuf gl_lds flash attn | out GEMM
// ---------------------------------------------------------------------------

typedef float f32x4 __attribute__((ext_vector_type(4)));
typedef float f32x16 __attribute__((ext_vector_type(16)));
typedef __bf16 bf16x8 __attribute__((ext_vector_type(8)));
typedef __bf16 bf16x4 __attribute__((ext_vector_type(4)));
typedef unsigned int u32;

#define MFMA16(a, b, c) __builtin_amdgcn_mfma_f32_16x16x32_bf16((a), (b), (c), 0, 0, 0)
#define MFMA32(a, b, c) __builtin_amdgcn_mfma_f32_32x32x16_bf16((a), (b), (c), 0, 0, 0)

#define GL16(gp, lp)                                                        \
  __builtin_amdgcn_global_load_lds(                                         \
      (const __attribute__((address_space(1))) void*)(gp),                  \
      (__attribute__((address_space(3))) void*)(lp), 16, 0, 0)

// ------------------------------- cvt f32 -> bf16 ---------------------------
__global__ void cvt_kernel(const float* __restrict__ src, __bf16* __restrict__ dst, int n4) {
  int i = blockIdx.x * blockDim.x + threadIdx.x;
  if (i < n4) {
    float4 v = ((const float4*)src)[i];
    bf16x4 o;
    o[0] = (__bf16)v.x; o[1] = (__bf16)v.y; o[2] = (__bf16)v.z; o[3] = (__bf16)v.w;
    ((bf16x4*)dst)[i] = o;
  }
}

// merged 4-weight cvt (dsts contiguous)
__global__ void cvt_w4(const float* __restrict__ wq, const float* __restrict__ wk,
                       const float* __restrict__ wv, const float* __restrict__ wo,
                       __bf16* __restrict__ dst) {
  int i = blockIdx.x * 256 + threadIdx.x;  // 4 * 262144 float4s
  int sel = i >> 18;
  const float* src = sel == 0 ? wq : sel == 1 ? wk : sel == 2 ? wv : wo;
  int j = i & 262143;
  float4 v = ((const float4*)src)[j];
  bf16x4 o;
  o[0] = (__bf16)v.x; o[1] = (__bf16)v.y; o[2] = (__bf16)v.z; o[3] = (__bf16)v.w;
  ((bf16x4*)dst)[i] = o;
}

// ------------------------------- RoPE table --------------------------------
__global__ void rope_table(float* __restrict__ ct, float* __restrict__ st) {
  int i = blockIdx.x * 256 + threadIdx.x;  // 65536 = 2048 pos * 32 freq
  int pos = i >> 5, f = i & 31;
  float inv = powf(10000.0f, -(float)f * (1.0f / 32.0f));
  float a = (float)pos * inv;
  ct[i] = cosf(a);
  st[i] = sinf(a);
}

// --------------------------- RoPE apply Q+K (in-place) ---------------------
__global__ void rope_apply2(__bf16* __restrict__ Qb, __bf16* __restrict__ Kb,
                            const int* __restrict__ tpos,
                            const float* __restrict__ ct, const float* __restrict__ st) {
  int tid = blockIdx.x * 256 + threadIdx.x;  // 2 * 4194304
  __bf16* buf = (tid & (1 << 22)) ? Kb : Qb;
  int id = tid & 4194303;
  int i = id & 31;
  int s = (id >> 5) & 2047;
  int b = id >> 20;
  int pos = tpos[(b << 11) + s];
  size_t base = (size_t)(id >> 5) * 64;
  float c = ct[(pos << 5) + i];
  float sn = st[(pos << 5) + i];
  float q1 = (float)buf[base + i];
  float q2 = (float)buf[base + 32 + i];
  buf[base + i] = (__bf16)(q1 * c - q2 * sn);
  buf[base + 32 + i] = (__bf16)(q2 * c + q1 * sn);
}

// ------------------------------- GEMM: C = A(MxK) * B(NxK)^T ----------------
// MODE 0: Q -> bf16 scatter (B,H,S,64), scaled by 0.125
// MODE 1: K -> bf16 scatter (B,H,S,64)
// MODE 2: V -> bf16 transposed (B*H, 64, 2048)   [V^T]
// MODE 3: out f32 row-major MxN
template <int MODE>
__global__ __launch_bounds__(256) void gemm_bt(const __bf16* __restrict__ A,
                                               const __bf16* __restrict__ Bw,
                                               void* __restrict__ Cout, int K) {
  __shared__ __align__(16) __bf16 As[128 * 32];
  __shared__ __align__(16) __bf16 Bs[128 * 32];
  const int t = threadIdx.x;
  const int w = t >> 6, l = t & 63;
  const int lr = l & 15, lg = l >> 4;
  const int wr = w >> 1, wc = w & 1;
  const int bm = blockIdx.x, bn = blockIdx.y;

  f32x4 acc[4][4] = {};

  const __bf16* ag = A + (size_t)(bm * 128 + (t >> 2)) * K + (t & 3) * 8;
  const __bf16* bg = Bw + (size_t)(bn * 128 + (t >> 2)) * K + (t & 3) * 8;
  __bf16* asl = As + w * 512;
  __bf16* bsl = Bs + w * 512;

  for (int kt = 0; kt < K; kt += 32) {
    GL16(ag + kt, asl);
    GL16(ag + kt + (size_t)64 * K, asl + 2048);
    GL16(bg + kt, bsl);
    GL16(bg + kt + (size_t)64 * K, bsl + 2048);
    __syncthreads();
    bf16x8 af[4], bf[4];
#pragma unroll
    for (int i = 0; i < 4; ++i) {
      af[i] = *(const bf16x8*)&As[(wr * 64 + i * 16 + lr) * 32 + lg * 8];
      bf[i] = *(const bf16x8*)&Bs[(wc * 64 + i * 16 + lr) * 32 + lg * 8];
    }
#pragma unroll
    for (int i = 0; i < 4; ++i)
#pragma unroll
      for (int j = 0; j < 4; ++j) acc[i][j] = MFMA16(af[i], bf[j], acc[i][j]);
    __syncthreads();
  }

#pragma unroll
  for (int i = 0; i < 4; ++i)
#pragma unroll
    for (int j = 0; j < 4; ++j) {
      const int grow0 = bm * 128 + wr * 64 + i * 16 + lg * 4;
      const int gcol = bn * 128 + wc * 64 + j * 16 + lr;
      if (MODE == 2) {
        const int b = grow0 >> 11, s = grow0 & 2047;
        const int h = gcol >> 6, d = gcol & 63;
        bf16x4 vv;
#pragma unroll
        for (int e = 0; e < 4; ++e) vv[e] = (__bf16)acc[i][j][e];
        *(bf16x4*)&((__bf16*)Cout)[(((size_t)(b * 16 + h)) * 64 + d) * 2048 + s] = vv;
      } else {
#pragma unroll
        for (int e = 0; e < 4; ++e) {
          const int grow = grow0 + e;
          float v = acc[i][j][e];
          if (MODE == 0 || MODE == 1) {
            if (MODE == 0) v *= 0.125f;
            const int b = grow >> 11, s = grow & 2047;
            const int h = gcol >> 6, d = gcol & 63;
            ((__bf16*)Cout)[(((size_t)(b * 16 + h)) * 2048 + s) * 64 + d] = (__bf16)v;
          } else {
            ((float*)Cout)[(size_t)grow * 1024 + gcol] = v;
          }
        }
      }
    }
}

// ------------------------- swapped-QK^T flash attention --------------------
// grid 1024 blocks; XCD-locality remap; 4 warps x 32 q rows (128 q / block).
// K and V^T staged via global_load_lds (linear dest, inverse-swizzled source),
// double-buffered; fragment ds_read_b128 with XOR swizzle (conflict-free).

static __device__ __forceinline__ u32 pk2(float a, float b) {
  union { __bf16 h[2]; u32 w; } u;
  u.h[0] = (__bf16)a; u.h[1] = (__bf16)b;
  return u.w;
}

#define PACK_FRAG(SRC, OFF, OUT)                                            \
  {                                                                         \
    u32 c01 = pk2(SRC[(OFF) + 0], SRC[(OFF) + 1]);                          \
    u32 c23 = pk2(SRC[(OFF) + 2], SRC[(OFF) + 3]);                          \
    u32 c45 = pk2(SRC[(OFF) + 4], SRC[(OFF) + 5]);                          \
    u32 c67 = pk2(SRC[(OFF) + 6], SRC[(OFF) + 7]);                          \
    u32 x1_ = (u32)__shfl_xor((int)(hi ? c01 : c45), 32);                   \
    u32 x2_ = (u32)__shfl_xor((int)(hi ? c23 : c67), 32);                   \
    union { u32 w[4]; bf16x8 v; } fu_;                                      \
    fu_.w[0] = hi ? x1_ : c01;                                              \
    fu_.w[1] = hi ? x2_ : c23;                                              \
    fu_.w[2] = hi ? c45 : x1_;                                              \
    fu_.w[3] = hi ? c67 : x2_;                                              \
    OUT = fu_.v;                                                            \
  }

// logical (row, col-byte) -> swizzled LDS byte offset
#define LDSOFF(row, cb) ((row) * 128 + ((cb) ^ (((row) & 7) << 4)))

__global__ __launch_bounds__(256) void attn_fwd(const __bf16* __restrict__ Q,
                                                const __bf16* __restrict__ Kb,
                                                const __bf16* __restrict__ VTg,
                                                __bf16* __restrict__ O) {
  __shared__ __align__(16) __bf16 Ks[2][64 * 64];
  __shared__ __align__(16) __bf16 Vs[2][64 * 64];
  const int t = threadIdx.x, w = t >> 6, l = t & 63;
  const int lq = l & 31, hi = l >> 5;
  // XCD-locality remap: all 16 q-blocks of a head on one XCD, heavy-first
  const int id = blockIdx.y * 16 + blockIdx.x;  // dispatch-linear 0..1023
  const int bh = (id & 7) * 8 + ((id >> 3) >> 4);
  const int qb = 15 - ((id >> 3) & 15);
  const int q0w = qb * 128 + w * 32;
  const int qrow = q0w + lq;
  const size_t kbaseB = (size_t)bh * (2048 * 64 * 2);  // K bytes
  const size_t vbaseB = (size_t)bh * (64 * 2048 * 2);  // V^T bytes

  // staging: thread t handles LDS bytes [t*16, t*16+16) of each 4KB chunk
  const int srow = t >> 3;                                  // 0..31
  const int scolb = ((t & 7) * 16) ^ ((srow & 7) << 4);     // inverse swizzle
  const char* kgp = (const char*)Kb + kbaseB + (size_t)srow * 128 + scolb;
  const char* vgp = (const char*)VTg + vbaseB + (size_t)srow * 4096 + scolb;
  char* kl = (char*)&Ks[0][0] + w * 1024;  // wave-uniform dest
  char* vl = (char*)&Vs[0][0] + w * 1024;

#define STAGE(bi, K0)                                                      \
  {                                                                        \
    GL16(kgp + (size_t)(K0) * 128, kl + (bi) * 8192);                      \
    GL16(kgp + (size_t)(K0) * 128 + 32 * 128, kl + (bi) * 8192 + 4096);    \
    GL16(vgp + (size_t)(K0) * 2, vl + (bi) * 8192);                        \
    GL16(vgp + (size_t)(K0) * 2 + 32 * 4096, vl + (bi) * 8192 + 4096);     \
  }

  // Q B-fragments (scale already folded into Q by GEMM)
  bf16x8 qf[4];
  const size_t qbase = (size_t)bh * (2048 * 64) + (size_t)qrow * 64;
#pragma unroll
  for (int ds = 0; ds < 4; ++ds)
    qf[ds] = *(const bf16x8*)&Q[qbase + ds * 16 + hi * 8];

  f32x16 ot0 = {}, ot1 = {};
  float mrun = -1e30f, lrun = 0.0f;

  const int nkt = qb * 2 + 2;
  STAGE(0, 0)
  __syncthreads();
  int cur = 0;
  for (int kt = 0; kt < nkt; ++kt) {
    const int k0 = kt * 64;
    if (kt + 1 < nkt) STAGE(cur ^ 1, k0 + 64)
    const char* kc = (const char*)&Ks[cur][0];
    const char* vc = (const char*)&Vs[cur][0];

    if (k0 <= q0w + 31) {
      // S^T: rows k (reg-mapped), col q = lane&31
      f32x16 st0 = {}, st1 = {};
      __builtin_amdgcn_s_setprio(1);
#pragma unroll
      for (int ds = 0; ds < 4; ++ds) {
        bf16x8 kf = *(const bf16x8*)(kc + LDSOFF(lq, ds * 32 + hi * 16));
        st0 = MFMA32(kf, qf[ds], st0);
      }
#pragma unroll
      for (int ds = 0; ds < 4; ++ds) {
        bf16x8 kf = *(const bf16x8*)(kc + LDSOFF(32 + lq, ds * 32 + hi * 16));
        st1 = MFMA32(kf, qf[ds], st1);
      }
      __builtin_amdgcn_s_setprio(0);

      float pmax = -1e30f;
      const bool full = (k0 + 63 <= q0w);
      if (full) {
#pragma unroll
        for (int r = 0; r < 16; ++r) pmax = fmaxf(pmax, fmaxf(st0[r], st1[r]));
      } else {
#pragma unroll
        for (int r = 0; r < 16; ++r) {
          int kl_ = k0 + (r & 3) + 8 * (r >> 2) + 4 * hi;
          float s0 = (kl_ > qrow) ? -1e30f : st0[r];
          float s1 = (kl_ + 32 > qrow) ? -1e30f : st1[r];
          st0[r] = s0;
          st1[r] = s1;
          pmax = fmaxf(pmax, fmaxf(s0, s1));
        }
      }
      pmax = fmaxf(pmax, __shfl_xor(pmax, 32));

      if (!__all(pmax <= mrun)) {
        float nm = fmaxf(mrun, pmax);
        float corr = __expf(mrun - nm);
        mrun = nm;
        lrun *= corr;
#pragma unroll
        for (int r = 0; r < 16; ++r) { ot0[r] *= corr; ot1[r] *= corr; }
      }

      float rs = 0.0f;
#pragma unroll
      for (int r = 0; r < 16; ++r) {
        float e0 = __expf(st0[r] - mrun);
        float e1 = __expf(st1[r] - mrun);
        st0[r] = e0; st1[r] = e1;
        rs += e0 + e1;
      }
      rs += __shfl_xor(rs, 32);
      lrun += rs;

      bf16x8 pa[4];
      PACK_FRAG(st0, 0, pa[0])
      PACK_FRAG(st0, 8, pa[1])
      PACK_FRAG(st1, 0, pa[2])
      PACK_FRAG(st1, 8, pa[3])

      __builtin_amdgcn_s_setprio(1);
#pragma unroll
      for (int fi = 0; fi < 4; ++fi) {
        bf16x8 vf = *(const bf16x8*)(vc + LDSOFF(lq, fi * 32 + hi * 16));
        ot0 = MFMA32(vf, pa[fi], ot0);
      }
#pragma unroll
      for (int fi = 0; fi < 4; ++fi) {
        bf16x8 vf = *(const bf16x8*)(vc + LDSOFF(32 + lq, fi * 32 + hi * 16));
        ot1 = MFMA32(vf, pa[fi], ot1);
      }
      __builtin_amdgcn_s_setprio(0);
    }
    __syncthreads();
    cur ^= 1;
  }

  // epilogue: O^T reg r -> d = dtile*32 + (r&3) + 8*(r>>2) + 4*hi, q = lane&31
  const int b = bh >> 4, h = bh & 15;
  float inv = 1.0f / lrun;
  __bf16* orow = O + ((size_t)(b * 2048 + qrow)) * 1024 + h * 64;
#pragma unroll
  for (int rq = 0; rq < 4; ++rq) {
    bf16x4 v0, v1;
#pragma unroll
    for (int e = 0; e < 4; ++e) {
      v0[e] = (__bf16)(ot0[rq * 4 + e] * inv);
      v1[e] = (__bf16)(ot1[rq * 4 + e] * inv);
    }
    *(bf16x4*)&orow[8 * rq + 4 * hi] = v0;
    *(bf16x4*)&orow[32 + 8 * rq + 4 * hi] = v1;
  }
}

// ---------------------------------------------------------------------------
extern "C" void kernel_launch(void* const* d_in, const int* in_sizes, int n_in,
                              void* d_out, int out_size, void* d_ws, size_t ws_size,
                              hipStream_t stream) {
  const float* x = (const float*)d_in[0];
  const float* wq = (const float*)d_in[1];
  const float* wk = (const float*)d_in[2];
  const float* wv = (const float*)d_in[3];
  const float* wo = (const float*)d_in[4];
  const int* tpos = (const int*)d_in[5];
  float* out = (float*)d_out;

  const size_t SZ_X = 8192u * 1024u * 2u;
  const size_t SZ_W = 1024u * 1024u * 2u;
  const size_t SZ_T = 2048u * 32u * 4u;
  const size_t NEED = SZ_X * 4 + SZ_W * 4 + SZ_T * 2;
  if (ws_size < NEED) return;

  char* p = (char*)d_ws;
  __bf16* xb  = (__bf16*)p; p += SZ_X;   // reused as attention output (AO)
  __bf16* wqb = (__bf16*)p; p += SZ_W;   // 4 weights contiguous
  __bf16* wkb = (__bf16*)p; p += SZ_W;
  __bf16* wvb = (__bf16*)p; p += SZ_W;
  __bf16* wob = (__bf16*)p; p += SZ_W;
  __bf16* Qb  = (__bf16*)p; p += SZ_X;
  __bf16* Kbf = (__bf16*)p; p += SZ_X;
  __bf16* VTg = (__bf16*)p; p += SZ_X;   // V^T (B*H, 64, 2048)
  float* ct = (float*)p; p += SZ_T;
  float* st = (float*)p; p += SZ_T;
  __bf16* AOb = xb;

  cvt_kernel<<<8192, 256, 0, stream>>>(x, xb, 2097152);
  cvt_w4<<<4096, 256, 0, stream>>>(wq, wk, wv, wo, wqb);
  rope_table<<<256, 256, 0, stream>>>(ct, st);

  gemm_bt<0><<<dim3(64, 8), 256, 0, stream>>>(xb, wqb, (void*)Qb, 1024);
  gemm_bt<1><<<dim3(64, 8), 256, 0, stream>>>(xb, wkb, (void*)Kbf, 1024);
  gemm_bt<2><<<dim3(64, 8), 256, 0, stream>>>(xb, wvb, (void*)VTg, 1024);

  rope_apply2<<<32768, 256, 0, stream>>>(Qb, Kbf, tpos, ct, st);

  attn_fwd<<<dim3(16, 64), 256, 0, stream>>>(Qb, Kbf, VTg, AOb);

  gemm_bt<3><<<dim3(64, 8), 256, 0, stream>>>(AOb, wob, (void*)out, 1024);
}

// Round 5
// 218.244 us; speedup vs baseline: 2.5699x; 1.2776x over previous
//
#include <hip/hip_runtime.h>

// ---------------------------------------------------------------------------
// MultiHeadSelfAttentionWithRoPE: B=4, S=2048, D_MODEL=1024, H=16, D_K=64
// cvt->bf16 | QKV GEMMs (RoPE+scale fused; V written transposed) |
// paired-causal 8-warp flash attn (counted vmcnt dbuf) | out GEMM
// ---------------------------------------------------------------------------

typedef float f32x4 __attribute__((ext_vector_type(4)));
typedef float f32x16 __attribute__((ext_vector_type(16)));
typedef __bf16 bf16x8 __attribute__((ext_vector_type(8)));
typedef __bf16 bf16x4 __attribute__((ext_vector_type(4)));
typedef unsigned int u32;

#define MFMA16(a, b, c) __builtin_amdgcn_mfma_f32_16x16x32_bf16((a), (b), (c), 0, 0, 0)
#define MFMA32(a, b, c) __builtin_amdgcn_mfma_f32_32x32x16_bf16((a), (b), (c), 0, 0, 0)

#define GL16(gp, lp)                                                        \
  __builtin_amdgcn_global_load_lds(                                         \
      (const __attribute__((address_space(1))) void*)(gp),                  \
      (__attribute__((address_space(3))) void*)(lp), 16, 0, 0)

// v_exp_f32: D = 2^S0 (one instruction)
#define EXP2(x) __builtin_amdgcn_exp2f(x)

// QK^T scores arrive pre-multiplied by 0.125*log2(e) (folded into Q) -> exp2.
#define QSCALE 0.18033688011112042f

// ------------------------------- cvt f32 -> bf16 ---------------------------
__global__ void cvt_kernel(const float* __restrict__ src, __bf16* __restrict__ dst, int n4) {
  int i = blockIdx.x * blockDim.x + threadIdx.x;
  if (i < n4) {
    float4 v = ((const float4*)src)[i];
    bf16x4 o;
    o[0] = (__bf16)v.x; o[1] = (__bf16)v.y; o[2] = (__bf16)v.z; o[3] = (__bf16)v.w;
    ((bf16x4*)dst)[i] = o;
  }
}

// merged 4-weight cvt (dsts contiguous)
__global__ void cvt_w4(const float* __restrict__ wq, const float* __restrict__ wk,
                       const float* __restrict__ wv, const float* __restrict__ wo,
                       __bf16* __restrict__ dst) {
  int i = blockIdx.x * 256 + threadIdx.x;  // 4 * 262144 float4s
  int sel = i >> 18;
  const float* src = sel == 0 ? wq : sel == 1 ? wk : sel == 2 ? wv : wo;
  int j = i & 262143;
  float4 v = ((const float4*)src)[j];
  bf16x4 o;
  o[0] = (__bf16)v.x; o[1] = (__bf16)v.y; o[2] = (__bf16)v.z; o[3] = (__bf16)v.w;
  ((bf16x4*)dst)[i] = o;
}

// ------------------------------- RoPE table --------------------------------
__global__ void rope_table(float* __restrict__ ct, float* __restrict__ st) {
  int i = blockIdx.x * 256 + threadIdx.x;  // 65536 = 2048 pos * 32 freq
  int pos = i >> 5, f = i & 31;
  float inv = powf(10000.0f, -(float)f * (1.0f / 32.0f));
  float a = (float)pos * inv;
  ct[i] = cosf(a);
  st[i] = sinf(a);
}

// ------------------------------- GEMM: C = A(MxK) * B(NxK)^T ----------------
// MODE 0: Q -> bf16 scatter (B,H,S,64), RoPE fused, scaled by 0.125*log2e
// MODE 1: K -> bf16 scatter (B,H,S,64), RoPE fused
// MODE 2: V -> bf16 transposed (B*H, 64, 2048)   [V^T]
// MODE 3: out f32 row-major MxN
template <int MODE>
__global__ __launch_bounds__(256) void gemm_bt(const __bf16* __restrict__ A,
                                               const __bf16* __restrict__ Bw,
                                               void* __restrict__ Cout, int K,
                                               const int* __restrict__ tpos,
                                               const float* __restrict__ ct,
                                               const float* __restrict__ st) {
  __shared__ __align__(16) __bf16 As[128 * 32];
  __shared__ __align__(16) __bf16 Bs[128 * 32];
  const int t = threadIdx.x;
  const int w = t >> 6, l = t & 63;
  const int lr = l & 15, lg = l >> 4;
  const int wr = w >> 1, wc = w & 1;
  const int bm = blockIdx.x, bn = blockIdx.y;

  f32x4 acc[4][4] = {};

  const __bf16* ag = A + (size_t)(bm * 128 + (t >> 2)) * K + (t & 3) * 8;
  const __bf16* bg = Bw + (size_t)(bn * 128 + (t >> 2)) * K + (t & 3) * 8;
  __bf16* asl = As + w * 512;
  __bf16* bsl = Bs + w * 512;

  for (int kt = 0; kt < K; kt += 32) {
    GL16(ag + kt, asl);
    GL16(ag + kt + (size_t)64 * K, asl + 2048);
    GL16(bg + kt, bsl);
    GL16(bg + kt + (size_t)64 * K, bsl + 2048);
    __syncthreads();
    bf16x8 af[4], bf[4];
#pragma unroll
    for (int i = 0; i < 4; ++i) {
      af[i] = *(const bf16x8*)&As[(wr * 64 + i * 16 + lr) * 32 + lg * 8];
      bf[i] = *(const bf16x8*)&Bs[(wc * 64 + i * 16 + lr) * 32 + lg * 8];
    }
#pragma unroll
    for (int i = 0; i < 4; ++i)
#pragma unroll
      for (int j = 0; j < 4; ++j) acc[i][j] = MFMA16(af[i], bf[j], acc[i][j]);
    __syncthreads();
  }

  if (MODE == 2) {
#pragma unroll
    for (int i = 0; i < 4; ++i)
#pragma unroll
      for (int j = 0; j < 4; ++j) {
        const int grow0 = bm * 128 + wr * 64 + i * 16 + lg * 4;
        const int gcol = bn * 128 + wc * 64 + j * 16 + lr;
        const int b = grow0 >> 11, s = grow0 & 2047;
        const int h = gcol >> 6, d = gcol & 63;
        bf16x4 vv;
#pragma unroll
        for (int e = 0; e < 4; ++e) vv[e] = (__bf16)acc[i][j][e];
        *(bf16x4*)&((__bf16*)Cout)[(((size_t)(b * 16 + h)) * 64 + d) * 2048 + s] = vv;
      }
  } else if (MODE == 3) {
#pragma unroll
    for (int i = 0; i < 4; ++i)
#pragma unroll
      for (int j = 0; j < 4; ++j)
#pragma unroll
        for (int e = 0; e < 4; ++e) {
          const int grow = bm * 128 + wr * 64 + i * 16 + lg * 4 + e;
          const int gcol = bn * 128 + wc * 64 + j * 16 + lr;
          ((float*)Cout)[(size_t)grow * 1024 + gcol] = acc[i][j][e];
        }
  } else {
    // Q/K: RoPE fused. acc[i][j] (d = j*16+lr) pairs with acc[i][j+2] (d+32).
    const int h = bn * 2 + wc;
#pragma unroll
    for (int i = 0; i < 4; ++i)
#pragma unroll
      for (int e = 0; e < 4; ++e) {
        const int grow = bm * 128 + wr * 64 + i * 16 + lg * 4 + e;
        const int pos = tpos[grow];  // grow = b*2048 + s
        const int b = grow >> 11, s = grow & 2047;
        __bf16* orow = &((__bf16*)Cout)[(((size_t)(b * 16 + h)) * 2048 + s) * 64];
#pragma unroll
        for (int j = 0; j < 2; ++j) {
          const int dd = j * 16 + lr;
          const float c = ct[pos * 32 + dd], sn = st[pos * 32 + dd];
          float x1 = acc[i][j][e], x2 = acc[i][j + 2][e];
          float o1 = x1 * c - x2 * sn;
          float o2 = x2 * c + x1 * sn;
          if (MODE == 0) { o1 *= QSCALE; o2 *= QSCALE; }
          orow[dd] = (__bf16)o1;
          orow[dd + 32] = (__bf16)o2;
        }
      }
  }
}

// ------------------------- paired-causal flash attention -------------------
// 256 blocks x 512 thr (8 warps x 32 q rows). Block handles q-blocks {p,7-p}
// (256 rows each) sharing one staged KV stream -> uniform work, 1 block/CU.
// K,V^T staged via global_load_lds (linear dest, inverse-swizzled source),
// double-buffered with counted s_waitcnt vmcnt(2) + raw barriers.

static __device__ __forceinline__ u32 pk2(float a, float b) {
  union { __bf16 h[2]; u32 w; } u;
  u.h[0] = (__bf16)a; u.h[1] = (__bf16)b;
  return u.w;
}

#define PACK_FRAG(SRC, OFF, OUT)                                            \
  {                                                                         \
    u32 c01 = pk2(SRC[(OFF) + 0], SRC[(OFF) + 1]);                          \
    u32 c23 = pk2(SRC[(OFF) + 2], SRC[(OFF) + 3]);                          \
    u32 c45 = pk2(SRC[(OFF) + 4], SRC[(OFF) + 5]);                          \
    u32 c67 = pk2(SRC[(OFF) + 6], SRC[(OFF) + 7]);                          \
    u32 x1_ = (u32)__shfl_xor((int)(hi ? c01 : c45), 32);                   \
    u32 x2_ = (u32)__shfl_xor((int)(hi ? c23 : c67), 32);                   \
    union { u32 w[4]; bf16x8 v; } fu_;                                      \
    fu_.w[0] = hi ? x1_ : c01;                                              \
    fu_.w[1] = hi ? x2_ : c23;                                              \
    fu_.w[2] = hi ? c45 : x1_;                                              \
    fu_.w[3] = hi ? c67 : x2_;                                              \
    OUT = fu_.v;                                                            \
  }

// logical (row, col-byte) -> swizzled LDS byte offset (128B rows)
#define LDSOFF(row, cb) ((row) * 128 + ((cb) ^ (((row) & 7) << 4)))

static __device__ __forceinline__ void attn_tile(
    const char* kc, const char* vc, int k0, int q0w, int qrow, int lq, int hi,
    const bf16x8* qf, float& mrun, float& lrun, f32x16& ot0, f32x16& ot1) {
  f32x16 st0 = {}, st1 = {};
  __builtin_amdgcn_s_setprio(1);
#pragma unroll
  for (int ds = 0; ds < 4; ++ds) {
    bf16x8 kf = *(const bf16x8*)(kc + LDSOFF(lq, ds * 32 + hi * 16));
    st0 = MFMA32(kf, qf[ds], st0);
  }
#pragma unroll
  for (int ds = 0; ds < 4; ++ds) {
    bf16x8 kf = *(const bf16x8*)(kc + LDSOFF(32 + lq, ds * 32 + hi * 16));
    st1 = MFMA32(kf, qf[ds], st1);
  }
  __builtin_amdgcn_s_setprio(0);

  float pmax = -1e30f;
  const bool full = (k0 + 63 <= q0w);
  if (full) {
#pragma unroll
    for (int r = 0; r < 16; ++r) pmax = fmaxf(pmax, fmaxf(st0[r], st1[r]));
  } else {
#pragma unroll
    for (int r = 0; r < 16; ++r) {
      int kl_ = k0 + (r & 3) + 8 * (r >> 2) + 4 * hi;
      float s0 = (kl_ > qrow) ? -1e30f : st0[r];
      float s1 = (kl_ + 32 > qrow) ? -1e30f : st1[r];
      st0[r] = s0;
      st1[r] = s1;
      pmax = fmaxf(pmax, fmaxf(s0, s1));
    }
  }
  pmax = fmaxf(pmax, __shfl_xor(pmax, 32));

  if (!__all(pmax <= mrun)) {
    float nm = fmaxf(mrun, pmax);
    float corr = EXP2(mrun - nm);
    mrun = nm;
    lrun *= corr;
#pragma unroll
    for (int r = 0; r < 16; ++r) { ot0[r] *= corr; ot1[r] *= corr; }
  }

  float rs = 0.0f;
#pragma unroll
  for (int r = 0; r < 16; ++r) {
    float e0 = EXP2(st0[r] - mrun);
    float e1 = EXP2(st1[r] - mrun);
    st0[r] = e0; st1[r] = e1;
    rs += e0 + e1;
  }
  rs += __shfl_xor(rs, 32);
  lrun += rs;

  bf16x8 pa[4];
  PACK_FRAG(st0, 0, pa[0])
  PACK_FRAG(st0, 8, pa[1])
  PACK_FRAG(st1, 0, pa[2])
  PACK_FRAG(st1, 8, pa[3])

  __builtin_amdgcn_s_setprio(1);
#pragma unroll
  for (int fi = 0; fi < 4; ++fi) {
    bf16x8 vf = *(const bf16x8*)(vc + LDSOFF(lq, fi * 32 + hi * 16));
    ot0 = MFMA32(vf, pa[fi], ot0);
  }
#pragma unroll
  for (int fi = 0; fi < 4; ++fi) {
    bf16x8 vf = *(const bf16x8*)(vc + LDSOFF(32 + lq, fi * 32 + hi * 16));
    ot1 = MFMA32(vf, pa[fi], ot1);
  }
  __builtin_amdgcn_s_setprio(0);
}

__global__ __launch_bounds__(512) void attn_fwd(const __bf16* __restrict__ Q,
                                                const __bf16* __restrict__ Kb,
                                                const __bf16* __restrict__ VTg,
                                                __bf16* __restrict__ O) {
  __shared__ __align__(16) __bf16 Ks[2][64 * 64];
  __shared__ __align__(16) __bf16 Vs[2][64 * 64];
  const int t = threadIdx.x, w = t >> 6, l = t & 63;
  const int lq = l & 31, hi = l >> 5;
  // id%8 = bh%8 -> all 4 pair-blocks of a head on one XCD (round-robin assump.)
  const int id = blockIdx.x;
  const int bh = (id & 7) + 8 * (id >> 5);
  const int p = (id >> 3) & 3;
  const int qbA = p, qbB = 7 - p;  // light + heavy = uniform 36 warp-tile-pairs
  const int qA0w = qbA * 256 + w * 32, qB0w = qbB * 256 + w * 32;
  const int qArow = qA0w + lq, qBrow = qB0w + lq;
  const size_t kbaseB = (size_t)bh * (2048 * 64 * 2);
  const size_t vbaseB = (size_t)bh * (64 * 2048 * 2);

  // staging: 512 threads x 16B = one full 64x64 bf16 tile per GL16 round
  const int srow = t >> 3;                               // 0..63
  const int scolb = ((t & 7) * 16) ^ ((srow & 7) << 4);  // inverse swizzle
  const char* kgp = (const char*)Kb + kbaseB + (size_t)srow * 128 + scolb;
  const char* vgp = (const char*)VTg + vbaseB + (size_t)srow * 4096 + scolb;
  char* kl = (char*)&Ks[0][0] + w * 1024;  // wave-uniform dest
  char* vl = (char*)&Vs[0][0] + w * 1024;

#define STAGE(bi, KT)                                                      \
  {                                                                        \
    GL16(kgp + (size_t)(KT) * 8192, kl + (bi) * 8192);                     \
    GL16(vgp + (size_t)(KT) * 128, vl + (bi) * 8192);                      \
  }

  // Q B-fragments (RoPE + 0.125*log2e already folded in by GEMM epilogue)
  const size_t qbase = (size_t)bh * (2048 * 64);
  bf16x8 qfA[4], qfB[4];
#pragma unroll
  for (int ds = 0; ds < 4; ++ds) {
    qfA[ds] = *(const bf16x8*)&Q[qbase + (size_t)qArow * 64 + ds * 16 + hi * 8];
    qfB[ds] = *(const bf16x8*)&Q[qbase + (size_t)qBrow * 64 + ds * 16 + hi * 8];
  }

  f32x16 oA0 = {}, oA1 = {}, oB0 = {}, oB1 = {};
  float mA = -1e30f, lA = 0.0f, mB = -1e30f, lB = 0.0f;

  const int nkt = 4 * qbB + 4;
  STAGE(0, 0)
  int cur = 0;
  for (int kt = 0; kt < nkt; ++kt) {
    const int k0 = kt * 64;
    if (kt + 1 < nkt) {
      STAGE(cur ^ 1, kt + 1)
      asm volatile("s_waitcnt vmcnt(2)" ::: "memory");
    } else {
      asm volatile("s_waitcnt vmcnt(0)" ::: "memory");
    }
    __builtin_amdgcn_s_barrier();
    __builtin_amdgcn_sched_barrier(0);
    const char* kc = (const char*)&Ks[cur][0];
    const char* vc = (const char*)&Vs[cur][0];

    if (k0 <= qB0w + 31)
      attn_tile(kc, vc, k0, qB0w, qBrow, lq, hi, qfB, mB, lB, oB0, oB1);
    if (k0 <= qA0w + 31)
      attn_tile(kc, vc, k0, qA0w, qArow, lq, hi, qfA, mA, lA, oA0, oA1);

    __builtin_amdgcn_s_barrier();
    cur ^= 1;
  }

  // epilogue: O^T reg r -> d = dtile*32 + (r&3) + 8*(r>>2) + 4*hi, q = lane&31
  const int b = bh >> 4, h = bh & 15;
  {
    float inv = 1.0f / lA;
    __bf16* orow = O + ((size_t)(b * 2048 + qArow)) * 1024 + h * 64;
#pragma unroll
    for (int rq = 0; rq < 4; ++rq) {
      bf16x4 v0, v1;
#pragma unroll
      for (int e = 0; e < 4; ++e) {
        v0[e] = (__bf16)(oA0[rq * 4 + e] * inv);
        v1[e] = (__bf16)(oA1[rq * 4 + e] * inv);
      }
      *(bf16x4*)&orow[8 * rq + 4 * hi] = v0;
      *(bf16x4*)&orow[32 + 8 * rq + 4 * hi] = v1;
    }
  }
  {
    float inv = 1.0f / lB;
    __bf16* orow = O + ((size_t)(b * 2048 + qBrow)) * 1024 + h * 64;
#pragma unroll
    for (int rq = 0; rq < 4; ++rq) {
      bf16x4 v0, v1;
#pragma unroll
      for (int e = 0; e < 4; ++e) {
        v0[e] = (__bf16)(oB0[rq * 4 + e] * inv);
        v1[e] = (__bf16)(oB1[rq * 4 + e] * inv);
      }
      *(bf16x4*)&orow[8 * rq + 4 * hi] = v0;
      *(bf16x4*)&orow[32 + 8 * rq + 4 * hi] = v1;
    }
  }
}

// ---------------------------------------------------------------------------
extern "C" void kernel_launch(void* const* d_in, const int* in_sizes, int n_in,
                              void* d_out, int out_size, void* d_ws, size_t ws_size,
                              hipStream_t stream) {
  const float* x = (const float*)d_in[0];
  const float* wq = (const float*)d_in[1];
  const float* wk = (const float*)d_in[2];
  const float* wv = (const float*)d_in[3];
  const float* wo = (const float*)d_in[4];
  const int* tpos = (const int*)d_in[5];
  float* out = (float*)d_out;

  const size_t SZ_X = 8192u * 1024u * 2u;
  const size_t SZ_W = 1024u * 1024u * 2u;
  const size_t SZ_T = 2048u * 32u * 4u;
  const size_t NEED = SZ_X * 4 + SZ_W * 4 + SZ_T * 2;
  if (ws_size < NEED) return;

  char* p = (char*)d_ws;
  __bf16* xb  = (__bf16*)p; p += SZ_X;   // reused as attention output (AO)
  __bf16* wqb = (__bf16*)p; p += SZ_W;   // 4 weights contiguous
  __bf16* wkb = (__bf16*)p; p += SZ_W;
  __bf16* wvb = (__bf16*)p; p += SZ_W;
  __bf16* wob = (__bf16*)p; p += SZ_W;
  __bf16* Qb  = (__bf16*)p; p += SZ_X;
  __bf16* Kbf = (__bf16*)p; p += SZ_X;
  __bf16* VTg = (__bf16*)p; p += SZ_X;   // V^T (B*H, 64, 2048)
  float* ct = (float*)p; p += SZ_T;
  float* st = (float*)p; p += SZ_T;
  __bf16* AOb = xb;

  cvt_kernel<<<8192, 256, 0, stream>>>(x, xb, 2097152);
  cvt_w4<<<4096, 256, 0, stream>>>(wq, wk, wv, wo, wqb);
  rope_table<<<256, 256, 0, stream>>>(ct, st);

  gemm_bt<0><<<dim3(64, 8), 256, 0, stream>>>(xb, wqb, (void*)Qb, 1024, tpos, ct, st);
  gemm_bt<1><<<dim3(64, 8), 256, 0, stream>>>(xb, wkb, (void*)Kbf, 1024, tpos, ct, st);
  gemm_bt<2><<<dim3(64, 8), 256, 0, stream>>>(xb, wvb, (void*)VTg, 1024, tpos, ct, st);

  attn_fwd<<<256, 512, 0, stream>>>(Qb, Kbf, VTg, AOb);

  gemm_bt<3><<<dim3(64, 8), 256, 0, stream>>>(AOb, wob, (void*)out, 1024, tpos, ct, st);
}

// Round 6
// 190.859 us; speedup vs baseline: 2.9387x; 1.1435x over previous
//
#include <hip/hip_runtime.h>

// ---------------------------------------------------------------------------
// MultiHeadSelfAttentionWithRoPE: B=4, S=2048, D_MODEL=1024, H=16, D_K=64
// cvt->bf16 | fused QKV GEMM (RoPE+scale fused; V transposed) |
// paired-causal 8-warp flash attn (KVBLK=128, counted vmcnt dbuf) | out GEMM
// ---------------------------------------------------------------------------

typedef float f32x4 __attribute__((ext_vector_type(4)));
typedef float f32x16 __attribute__((ext_vector_type(16)));
typedef __bf16 bf16x8 __attribute__((ext_vector_type(8)));
typedef __bf16 bf16x4 __attribute__((ext_vector_type(4)));
typedef unsigned int u32;

#define MFMA16(a, b, c) __builtin_amdgcn_mfma_f32_16x16x32_bf16((a), (b), (c), 0, 0, 0)
#define MFMA32(a, b, c) __builtin_amdgcn_mfma_f32_32x32x16_bf16((a), (b), (c), 0, 0, 0)

#define GL16(gp, lp)                                                        \
  __builtin_amdgcn_global_load_lds(                                         \
      (const __attribute__((address_space(1))) void*)(gp),                  \
      (__attribute__((address_space(3))) void*)(lp), 16, 0, 0)

// v_exp_f32: D = 2^S0 (one instruction)
#define EXP2(x) __builtin_amdgcn_exp2f(x)

// QK^T scores arrive pre-multiplied by 0.125*log2(e) (folded into Q) -> exp2.
#define QSCALE 0.18033688011112042f

// ------------------------------- cvt f32 -> bf16 ---------------------------
__global__ void cvt_kernel(const float* __restrict__ src, __bf16* __restrict__ dst, int n4) {
  int i = blockIdx.x * blockDim.x + threadIdx.x;
  if (i < n4) {
    float4 v = ((const float4*)src)[i];
    bf16x4 o;
    o[0] = (__bf16)v.x; o[1] = (__bf16)v.y; o[2] = (__bf16)v.z; o[3] = (__bf16)v.w;
    ((bf16x4*)dst)[i] = o;
  }
}

// merged 4-weight cvt (dsts contiguous)
__global__ void cvt_w4(const float* __restrict__ wq, const float* __restrict__ wk,
                       const float* __restrict__ wv, const float* __restrict__ wo,
                       __bf16* __restrict__ dst) {
  int i = blockIdx.x * 256 + threadIdx.x;  // 4 * 262144 float4s
  int sel = i >> 18;
  const float* src = sel == 0 ? wq : sel == 1 ? wk : sel == 2 ? wv : wo;
  int j = i & 262143;
  float4 v = ((const float4*)src)[j];
  bf16x4 o;
  o[0] = (__bf16)v.x; o[1] = (__bf16)v.y; o[2] = (__bf16)v.z; o[3] = (__bf16)v.w;
  ((bf16x4*)dst)[i] = o;
}

// ------------------------------- RoPE table --------------------------------
__global__ void rope_table(float* __restrict__ ct, float* __restrict__ st) {
  int i = blockIdx.x * 256 + threadIdx.x;  // 65536 = 2048 pos * 32 freq
  int pos = i >> 5, f = i & 31;
  float inv = powf(10000.0f, -(float)f * (1.0f / 32.0f));
  float a = (float)pos * inv;
  ct[i] = cosf(a);
  st[i] = sinf(a);
}

// ------------------------------- GEMM: C = A(MxK) * B(NxK)^T ----------------
// MODE 4: fused QKV (N=3072): bn<8 -> Q (RoPE+QSCALE), bn<16 -> K (RoPE),
//         else V^T (B*H, 64, 2048). Cout = Qb; K at +8M elems, V^T at +16M.
// MODE 3: out f32 row-major MxN (N=1024)
template <int MODE>
__global__ __launch_bounds__(256) void gemm_bt(const __bf16* __restrict__ A,
                                               const __bf16* __restrict__ Bw,
                                               void* __restrict__ Cout, int K,
                                               const int* __restrict__ tpos,
                                               const float* __restrict__ ct,
                                               const float* __restrict__ st) {
  __shared__ __align__(16) __bf16 As[2][128 * 32];
  __shared__ __align__(16) __bf16 Bs[2][128 * 32];
  const int t = threadIdx.x;
  const int w = t >> 6, l = t & 63;
  const int lr = l & 15, lg = l >> 4;
  const int wr = w >> 1, wc = w & 1;
  const int bm = blockIdx.x, bn = blockIdx.y;

  f32x4 acc[4][4] = {};

  const __bf16* ag = A + (size_t)(bm * 128 + (t >> 2)) * K + (t & 3) * 8;
  const __bf16* bg = Bw + (size_t)(bn * 128 + (t >> 2)) * K + (t & 3) * 8;
  __bf16* Asl = &As[0][0] + w * 512;  // wave-uniform LDS base
  __bf16* Bsl = &Bs[0][0] + w * 512;

#define GSTAGE(bi, KT)                                                     \
  {                                                                        \
    GL16(ag + (KT) * 32, Asl + (bi) * 4096);                               \
    GL16(ag + (KT) * 32 + (size_t)64 * K, Asl + (bi) * 4096 + 2048);       \
    GL16(bg + (KT) * 32, Bsl + (bi) * 4096);                               \
    GL16(bg + (KT) * 32 + (size_t)64 * K, Bsl + (bi) * 4096 + 2048);       \
  }

  const int nk = K >> 5;
  GSTAGE(0, 0)
  int cur = 0;
  for (int kt = 0; kt < nk; ++kt) {
    if (kt + 1 < nk) {
      GSTAGE(cur ^ 1, kt + 1)
      asm volatile("s_waitcnt vmcnt(4)" ::: "memory");
    } else {
      asm volatile("s_waitcnt vmcnt(0)" ::: "memory");
    }
    __builtin_amdgcn_s_barrier();
    __builtin_amdgcn_sched_barrier(0);
    bf16x8 af[4], bf[4];
#pragma unroll
    for (int i = 0; i < 4; ++i) {
      af[i] = *(const bf16x8*)&As[cur][(wr * 64 + i * 16 + lr) * 32 + lg * 8];
      bf[i] = *(const bf16x8*)&Bs[cur][(wc * 64 + i * 16 + lr) * 32 + lg * 8];
    }
    __builtin_amdgcn_s_setprio(1);
#pragma unroll
    for (int i = 0; i < 4; ++i)
#pragma unroll
      for (int j = 0; j < 4; ++j) acc[i][j] = MFMA16(af[i], bf[j], acc[i][j]);
    __builtin_amdgcn_s_setprio(0);
    __builtin_amdgcn_s_barrier();
    cur ^= 1;
  }

  if (MODE == 3) {
#pragma unroll
    for (int i = 0; i < 4; ++i)
#pragma unroll
      for (int j = 0; j < 4; ++j)
#pragma unroll
        for (int e = 0; e < 4; ++e) {
          const int grow = bm * 128 + wr * 64 + i * 16 + lg * 4 + e;
          const int gcol = bn * 128 + wc * 64 + j * 16 + lr;
          ((float*)Cout)[(size_t)grow * 1024 + gcol] = acc[i][j][e];
        }
  } else {
    const int seg = bn >> 3;   // 0=Q 1=K 2=V
    const int bnn = bn & 7;
    if (seg < 2) {
      // Q/K: RoPE fused. acc[i][j] (d=j*16+lr) pairs with acc[i][j+2] (d+32).
      const int h = bnn * 2 + wc;
      __bf16* base = (__bf16*)Cout + (size_t)seg * 8388608;
#pragma unroll
      for (int i = 0; i < 4; ++i)
#pragma unroll
        for (int e = 0; e < 4; ++e) {
          const int grow = bm * 128 + wr * 64 + i * 16 + lg * 4 + e;
          const int pos = tpos[grow];  // grow = b*2048 + s
          const int b = grow >> 11, s = grow & 2047;
          __bf16* orow = &base[(((size_t)(b * 16 + h)) * 2048 + s) * 64];
#pragma unroll
          for (int j = 0; j < 2; ++j) {
            const int dd = j * 16 + lr;
            const float c = ct[pos * 32 + dd], sn = st[pos * 32 + dd];
            float x1 = acc[i][j][e], x2 = acc[i][j + 2][e];
            float o1 = x1 * c - x2 * sn;
            float o2 = x2 * c + x1 * sn;
            if (seg == 0) { o1 *= QSCALE; o2 *= QSCALE; }
            orow[dd] = (__bf16)o1;
            orow[dd + 32] = (__bf16)o2;
          }
        }
    } else {
      __bf16* base = (__bf16*)Cout + 16777216;
#pragma unroll
      for (int i = 0; i < 4; ++i)
#pragma unroll
        for (int j = 0; j < 4; ++j) {
          const int grow0 = bm * 128 + wr * 64 + i * 16 + lg * 4;
          const int gcol = bnn * 128 + wc * 64 + j * 16 + lr;
          const int b = grow0 >> 11, s = grow0 & 2047;
          const int h = gcol >> 6, d = gcol & 63;
          bf16x4 vv;
#pragma unroll
          for (int e = 0; e < 4; ++e) vv[e] = (__bf16)acc[i][j][e];
          *(bf16x4*)&base[(((size_t)(b * 16 + h)) * 64 + d) * 2048 + s] = vv;
        }
    }
  }
}

// ------------------------- paired-causal flash attention -------------------
// 256 blocks x 512 thr (8 warps x 32 q). Block = q-blocks {p,7-p} (256 rows
// each) sharing one KV stream; KVBLK=128 staged per barrier round (2 subtiles).
// Phase-split dual-tile processing for VALU-chain ILP.

static __device__ __forceinline__ u32 pk2(float a, float b) {
  union { __bf16 h[2]; u32 w; } u;
  u.h[0] = (__bf16)a; u.h[1] = (__bf16)b;
  return u.w;
}

#define PACK_FRAG(SRC, OFF, OUT)                                            \
  {                                                                         \
    u32 c01 = pk2(SRC[(OFF) + 0], SRC[(OFF) + 1]);                          \
    u32 c23 = pk2(SRC[(OFF) + 2], SRC[(OFF) + 3]);                          \
    u32 c45 = pk2(SRC[(OFF) + 4], SRC[(OFF) + 5]);                          \
    u32 c67 = pk2(SRC[(OFF) + 6], SRC[(OFF) + 7]);                          \
    u32 x1_ = (u32)__shfl_xor((int)(hi ? c01 : c45), 32);                   \
    u32 x2_ = (u32)__shfl_xor((int)(hi ? c23 : c67), 32);                   \
    union { u32 w[4]; bf16x8 v; } fu_;                                      \
    fu_.w[0] = hi ? x1_ : c01;                                              \
    fu_.w[1] = hi ? x2_ : c23;                                              \
    fu_.w[2] = hi ? c45 : x1_;                                              \
    fu_.w[3] = hi ? c67 : x2_;                                              \
    OUT = fu_.v;                                                            \
  }

// K tile: 128B rows; V^T tile: 256B rows; XOR swizzle on 16B slots
#define KOFF(row, cb) ((row) * 128 + ((cb) ^ (((row) & 7) << 4)))
#define VOFF(row, cb) ((row) * 256 + ((cb) ^ (((row) & 7) << 4)))

static __device__ __forceinline__ void qkt(const char* kcs, const bf16x8* qf,
                                           int lq, int hi, f32x16& s0, f32x16& s1) {
  s0 = (f32x16){}; s1 = (f32x16){};
#pragma unroll
  for (int ds = 0; ds < 4; ++ds) {
    bf16x8 kf = *(const bf16x8*)(kcs + KOFF(lq, ds * 32 + hi * 16));
    s0 = MFMA32(kf, qf[ds], s0);
  }
#pragma unroll
  for (int ds = 0; ds < 4; ++ds) {
    bf16x8 kf = *(const bf16x8*)(kcs + KOFF(32 + lq, ds * 32 + hi * 16));
    s1 = MFMA32(kf, qf[ds], s1);
  }
}

static __device__ __forceinline__ float maskmax(f32x16& s0, f32x16& s1, int k0,
                                                int q0w, int qrow, int hi) {
  if (k0 + 63 > q0w) {  // edge tile: apply causal mask
#pragma unroll
    for (int r = 0; r < 16; ++r) {
      int kl_ = k0 + (r & 3) + 8 * (r >> 2) + 4 * hi;
      s0[r] = (kl_ > qrow) ? -1e30f : s0[r];
      s1[r] = (kl_ + 32 > qrow) ? -1e30f : s1[r];
    }
  }
  float m[8];
#pragma unroll
  for (int r = 0; r < 8; ++r)
    m[r] = fmaxf(fmaxf(s0[r], s0[r + 8]), fmaxf(s1[r], s1[r + 8]));
#pragma unroll
  for (int r = 0; r < 4; ++r) m[r] = fmaxf(m[r], m[r + 4]);
  float pm = fmaxf(fmaxf(m[0], m[1]), fmaxf(m[2], m[3]));
  return fmaxf(pm, __shfl_xor(pm, 32));
}

static __device__ __forceinline__ void smpack(f32x16& s0, f32x16& s1, float pmax,
                                              float& mrun, float& lrun,
                                              f32x16& o0, f32x16& o1,
                                              bf16x8* pa, int hi) {
  if (!__all(pmax <= mrun + 8.0f)) {  // defer-max: P bounded by 2^8
    float nm = fmaxf(mrun, pmax);
    float corr = EXP2(mrun - nm);
    mrun = nm;
    lrun *= corr;
#pragma unroll
    for (int r = 0; r < 16; ++r) { o0[r] *= corr; o1[r] *= corr; }
  }
  float rsp0 = 0.f, rsp1 = 0.f, rsp2 = 0.f, rsp3 = 0.f;
#pragma unroll
  for (int r = 0; r < 4; ++r) {
    float e0 = EXP2(s0[r] - mrun), e1 = EXP2(s0[r + 4] - mrun);
    float e2 = EXP2(s0[r + 8] - mrun), e3 = EXP2(s0[r + 12] - mrun);
    s0[r] = e0; s0[r + 4] = e1; s0[r + 8] = e2; s0[r + 12] = e3;
    rsp0 += e0; rsp1 += e1; rsp2 += e2; rsp3 += e3;
  }
#pragma unroll
  for (int r = 0; r < 4; ++r) {
    float e0 = EXP2(s1[r] - mrun), e1 = EXP2(s1[r + 4] - mrun);
    float e2 = EXP2(s1[r + 8] - mrun), e3 = EXP2(s1[r + 12] - mrun);
    s1[r] = e0; s1[r + 4] = e1; s1[r + 8] = e2; s1[r + 12] = e3;
    rsp0 += e0; rsp1 += e1; rsp2 += e2; rsp3 += e3;
  }
  float rs = (rsp0 + rsp1) + (rsp2 + rsp3);
  rs += __shfl_xor(rs, 32);
  lrun += rs;
  PACK_FRAG(s0, 0, pa[0])
  PACK_FRAG(s0, 8, pa[1])
  PACK_FRAG(s1, 0, pa[2])
  PACK_FRAG(s1, 8, pa[3])
}

static __device__ __forceinline__ void pv(const char* vc, int vcb0, int lq, int hi,
                                          const bf16x8* pa, f32x16& o0, f32x16& o1) {
#pragma unroll
  for (int fi = 0; fi < 4; ++fi) {
    bf16x8 vf = *(const bf16x8*)(vc + VOFF(lq, vcb0 + fi * 32 + hi * 16));
    o0 = MFMA32(vf, pa[fi], o0);
  }
#pragma unroll
  for (int fi = 0; fi < 4; ++fi) {
    bf16x8 vf = *(const bf16x8*)(vc + VOFF(32 + lq, vcb0 + fi * 32 + hi * 16));
    o1 = MFMA32(vf, pa[fi], o1);
  }
}

__global__ __launch_bounds__(512) void attn_fwd(const __bf16* __restrict__ Q,
                                                const __bf16* __restrict__ Kb,
                                                const __bf16* __restrict__ VTg,
                                                __bf16* __restrict__ O) {
  __shared__ __align__(16) __bf16 Ks[2][128 * 64];  // [k=128][d], 128B rows
  __shared__ __align__(16) __bf16 Vs[2][64 * 128];  // [d=64][k], 256B rows
  const int t = threadIdx.x, w = t >> 6, l = t & 63;
  const int lq = l & 31, hi = l >> 5;
  const int id = blockIdx.x;
  const int bh = (id & 7) + 8 * (id >> 5);  // same-head blocks share an XCD
  const int p = (id >> 3) & 3;
  const int qbA = p, qbB = 7 - p;  // uniform 36 warp-tile-pairs per block
  const int qA0w = qbA * 256 + w * 32, qB0w = qbB * 256 + w * 32;
  const int qArow = qA0w + lq, qBrow = qB0w + lq;
  const size_t kbaseB = (size_t)bh * (2048 * 64 * 2);
  const size_t vbaseB = (size_t)bh * (64 * 2048 * 2);

  // staging: 512 thr x 16B = 8KB per GL16; K tile 16KB (2x), V tile 16KB (2x)
  const int srow = t >> 3;                               // 0..63 (K rows)
  const int scolb = ((t & 7) * 16) ^ ((srow & 7) << 4);  // inverse swizzle
  const int vrow = t >> 4;                               // 0..31 (V rows)
  const int vcolb = ((t & 15) * 16) ^ ((vrow & 7) << 4);
  const char* kgp = (const char*)Kb + kbaseB + (size_t)srow * 128 + scolb;
  const char* vgp = (const char*)VTg + vbaseB + (size_t)vrow * 4096 + vcolb;
  char* kl = (char*)&Ks[0][0] + w * 1024;  // wave-uniform dest
  char* vl = (char*)&Vs[0][0] + w * 1024;

#define STAGE(bi, KT)                                                      \
  {                                                                        \
    GL16(kgp + (size_t)(KT) * 16384, kl + (bi) * 16384);                   \
    GL16(kgp + (size_t)(KT) * 16384 + 64 * 128, kl + (bi) * 16384 + 8192); \
    GL16(vgp + (size_t)(KT) * 256, vl + (bi) * 16384);                     \
    GL16(vgp + (size_t)(KT) * 256 + (size_t)32 * 4096,                     \
         vl + (bi) * 16384 + 8192);                                        \
  }

  // Q B-fragments (RoPE + 0.125*log2e already folded in by GEMM epilogue)
  const size_t qbase = (size_t)bh * (2048 * 64);
  bf16x8 qfA[4], qfB[4];
#pragma unroll
  for (int ds = 0; ds < 4; ++ds) {
    qfA[ds] = *(const bf16x8*)&Q[qbase + (size_t)qArow * 64 + ds * 16 + hi * 8];
    qfB[ds] = *(const bf16x8*)&Q[qbase + (size_t)qBrow * 64 + ds * 16 + hi * 8];
  }

  f32x16 oA0 = {}, oA1 = {}, oB0 = {}, oB1 = {};
  float mA = -1e30f, lA = 0.0f, mB = -1e30f, lB = 0.0f;

  const int nkt = 2 * qbB + 2;  // 128-wide KV tiles
  STAGE(0, 0)
  int cur = 0;
  for (int kt = 0; kt < nkt; ++kt) {
    if (kt + 1 < nkt) {
      STAGE(cur ^ 1, kt + 1)
      asm volatile("s_waitcnt vmcnt(4)" ::: "memory");
    } else {
      asm volatile("s_waitcnt vmcnt(0)" ::: "memory");
    }
    __builtin_amdgcn_s_barrier();
    __builtin_amdgcn_sched_barrier(0);
    const char* kc = (const char*)&Ks[cur][0];
    const char* vc = (const char*)&Vs[cur][0];

#pragma unroll
    for (int sub = 0; sub < 2; ++sub) {
      const int k0 = kt * 128 + sub * 64;
      const char* kcs = kc + sub * 8192;
      const int vcb0 = sub * 128;
      if (k0 > qB0w + 31) continue;  // warp-uniform
      const bool doA = (k0 <= qA0w + 31);  // warp-uniform

      f32x16 sB0, sB1, sA0, sA1;
      __builtin_amdgcn_s_setprio(1);
      qkt(kcs, qfB, lq, hi, sB0, sB1);
      if (doA) qkt(kcs, qfA, lq, hi, sA0, sA1);
      __builtin_amdgcn_s_setprio(0);

      float pmB = maskmax(sB0, sB1, k0, qB0w, qBrow, hi);
      bf16x8 paB[4], paA[4];
      if (doA) {
        float pmA = maskmax(sA0, sA1, k0, qA0w, qArow, hi);
        smpack(sB0, sB1, pmB, mB, lB, oB0, oB1, paB, hi);
        smpack(sA0, sA1, pmA, mA, lA, oA0, oA1, paA, hi);
        __builtin_amdgcn_s_setprio(1);
        pv(vc, vcb0, lq, hi, paB, oB0, oB1);
        pv(vc, vcb0, lq, hi, paA, oA0, oA1);
        __builtin_amdgcn_s_setprio(0);
      } else {
        smpack(sB0, sB1, pmB, mB, lB, oB0, oB1, paB, hi);
        __builtin_amdgcn_s_setprio(1);
        pv(vc, vcb0, lq, hi, paB, oB0, oB1);
        __builtin_amdgcn_s_setprio(0);
      }
    }
    __builtin_amdgcn_s_barrier();
    cur ^= 1;
  }

  // epilogue: O^T reg r -> d = dtile*32 + (r&3) + 8*(r>>2) + 4*hi, q = lane&31
  const int b = bh >> 4, h = bh & 15;
  {
    float inv = 1.0f / lA;
    __bf16* orow = O + ((size_t)(b * 2048 + qArow)) * 1024 + h * 64;
#pragma unroll
    for (int rq = 0; rq < 4; ++rq) {
      bf16x4 v0, v1;
#pragma unroll
      for (int e = 0; e < 4; ++e) {
        v0[e] = (__bf16)(oA0[rq * 4 + e] * inv);
        v1[e] = (__bf16)(oA1[rq * 4 + e] * inv);
      }
      *(bf16x4*)&orow[8 * rq + 4 * hi] = v0;
      *(bf16x4*)&orow[32 + 8 * rq + 4 * hi] = v1;
    }
  }
  {
    float inv = 1.0f / lB;
    __bf16* orow = O + ((size_t)(b * 2048 + qBrow)) * 1024 + h * 64;
#pragma unroll
    for (int rq = 0; rq < 4; ++rq) {
      bf16x4 v0, v1;
#pragma unroll
      for (int e = 0; e < 4; ++e) {
        v0[e] = (__bf16)(oB0[rq * 4 + e] * inv);
        v1[e] = (__bf16)(oB1[rq * 4 + e] * inv);
      }
      *(bf16x4*)&orow[8 * rq + 4 * hi] = v0;
      *(bf16x4*)&orow[32 + 8 * rq + 4 * hi] = v1;
    }
  }
}

// ---------------------------------------------------------------------------
extern "C" void kernel_launch(void* const* d_in, const int* in_sizes, int n_in,
                              void* d_out, int out_size, void* d_ws, size_t ws_size,
                              hipStream_t stream) {
  const float* x = (const float*)d_in[0];
  const float* wq = (const float*)d_in[1];
  const float* wk = (const float*)d_in[2];
  const float* wv = (const float*)d_in[3];
  const float* wo = (const float*)d_in[4];
  const int* tpos = (const int*)d_in[5];
  float* out = (float*)d_out;

  const size_t SZ_X = 8192u * 1024u * 2u;
  const size_t SZ_W = 1024u * 1024u * 2u;
  const size_t SZ_T = 2048u * 32u * 4u;
  const size_t NEED = SZ_X * 4 + SZ_W * 4 + SZ_T * 2;
  if (ws_size < NEED) return;

  char* p = (char*)d_ws;
  __bf16* xb  = (__bf16*)p; p += SZ_X;   // reused as attention output (AO)
  __bf16* wqb = (__bf16*)p; p += SZ_W;   // 4 weights contiguous (wq|wk|wv|wo)
  __bf16* wkb = (__bf16*)p; p += SZ_W;
  __bf16* wvb = (__bf16*)p; p += SZ_W;
  __bf16* wob = (__bf16*)p; p += SZ_W;
  __bf16* Qb  = (__bf16*)p; p += SZ_X;   // Q | K | V^T contiguous
  __bf16* Kbf = (__bf16*)p; p += SZ_X;
  __bf16* VTg = (__bf16*)p; p += SZ_X;
  float* ct = (float*)p; p += SZ_T;
  float* st = (float*)p; p += SZ_T;
  __bf16* AOb = xb;
  (void)wkb; (void)wvb;

  cvt_kernel<<<8192, 256, 0, stream>>>(x, xb, 2097152);
  cvt_w4<<<4096, 256, 0, stream>>>(wq, wk, wv, wo, wqb);
  rope_table<<<256, 256, 0, stream>>>(ct, st);

  // fused QKV: B = wq|wk|wv rows (contiguous), N=3072
  gemm_bt<4><<<dim3(64, 24), 256, 0, stream>>>(xb, wqb, (void*)Qb, 1024, tpos, ct, st);

  attn_fwd<<<256, 512, 0, stream>>>(Qb, Kbf, VTg, AOb);

  gemm_bt<3><<<dim3(64, 8), 256, 0, stream>>>(AOb, wob, (void*)out, 1024, tpos, ct, st);
}

// Round 7
// 188.023 us; speedup vs baseline: 2.9830x; 1.0151x over previous
//
#include <hip/hip_runtime.h>

// ---------------------------------------------------------------------------
// MultiHeadSelfAttentionWithRoPE: B=4, S=2048, D_MODEL=1024, H=16, D_K=64
// cvt->bf16 | phase-split 256x128 QKV GEMM (RoPE fused; V transposed) |
// paired-causal 8-warp flash attn | phase-split out GEMM
// ---------------------------------------------------------------------------

typedef float f32x4 __attribute__((ext_vector_type(4)));
typedef float f32x16 __attribute__((ext_vector_type(16)));
typedef __bf16 bf16x8 __attribute__((ext_vector_type(8)));
typedef __bf16 bf16x4 __attribute__((ext_vector_type(4)));
typedef unsigned int u32;

#define MFMA16(a, b, c) __builtin_amdgcn_mfma_f32_16x16x32_bf16((a), (b), (c), 0, 0, 0)
#define MFMA32(a, b, c) __builtin_amdgcn_mfma_f32_32x32x16_bf16((a), (b), (c), 0, 0, 0)

#define GL16(gp, lp)                                                        \
  __builtin_amdgcn_global_load_lds(                                         \
      (const __attribute__((address_space(1))) void*)(gp),                  \
      (__attribute__((address_space(3))) void*)(lp), 16, 0, 0)

#define EXP2(x) __builtin_amdgcn_exp2f(x)
#define QSCALE 0.18033688011112042f

// ------------------------------- cvt f32 -> bf16 ---------------------------
__global__ void cvt_kernel(const float* __restrict__ src, __bf16* __restrict__ dst, int n4) {
  int i = blockIdx.x * blockDim.x + threadIdx.x;
  if (i < n4) {
    float4 v = ((const float4*)src)[i];
    bf16x4 o;
    o[0] = (__bf16)v.x; o[1] = (__bf16)v.y; o[2] = (__bf16)v.z; o[3] = (__bf16)v.w;
    ((bf16x4*)dst)[i] = o;
  }
}

__global__ void cvt_w4(const float* __restrict__ wq, const float* __restrict__ wk,
                       const float* __restrict__ wv, const float* __restrict__ wo,
                       __bf16* __restrict__ dst) {
  int i = blockIdx.x * 256 + threadIdx.x;
  int sel = i >> 18;
  const float* src = sel == 0 ? wq : sel == 1 ? wk : sel == 2 ? wv : wo;
  int j = i & 262143;
  float4 v = ((const float4*)src)[j];
  bf16x4 o;
  o[0] = (__bf16)v.x; o[1] = (__bf16)v.y; o[2] = (__bf16)v.z; o[3] = (__bf16)v.w;
  ((bf16x4*)dst)[i] = o;
}

// ------------------------------- RoPE table --------------------------------
__global__ void rope_table(float* __restrict__ ct, float* __restrict__ st) {
  int i = blockIdx.x * 256 + threadIdx.x;
  int pos = i >> 5, f = i & 31;
  float inv = powf(10000.0f, -(float)f * (1.0f / 32.0f));
  float a = (float)pos * inv;
  ct[i] = cosf(a);
  st[i] = sinf(a);
}

// --------------- phase-split GEMM: C = A(8192xK) * B(NxK)^T ----------------
// BM=256, BN=128, BK=64, 512 thr = 8 waves (4M x 2N), per-wave 64x64.
// LDS 96KB: A dbuf 2x32KB, B dbuf 2x16KB; XOR-swizzled 16B slots.
// Per K-tile: 2 phases x 16 MFMA; stages threaded at region-free points;
// counted vmcnt(4) at tile boundary (never 0 mid-loop).
// MODE 4: fused QKV (N=3072): seg 0=Q(RoPE+QSCALE) 1=K(RoPE) 2=V^T
// MODE 3: out f32 (N=1024)
template <int MODE>
__global__ __launch_bounds__(512, 2) void gemm8(const __bf16* __restrict__ A,
                                                const __bf16* __restrict__ Bw,
                                                void* __restrict__ Cout,
                                                const int* __restrict__ tpos,
                                                const float* __restrict__ ct,
                                                const float* __restrict__ st) {
  __shared__ __align__(16) char LB[98304];
  const int nk = 16;  // K=1024 / BK=64
  const int t = threadIdx.x, w = t >> 6, l = t & 63;
  const int lr = l & 15, lg = l >> 4;
  const int wr = w >> 1, wc = w & 1;
  // XCD swizzle: grid % 8 == 0 (768 or 256)
  const int id = blockIdx.x;
  const int cpx = (MODE == 4) ? 96 : 32;
  const int g = (id & 7) * cpx + (id >> 3);
  const int bm = g & 31, bn = g >> 5;

  // staging: thread t covers linear LDS bytes t*16 (+8192) per unit;
  // global source col pre-swizzled (inverse of read swizzle)
  const int srow = t >> 3;
  const int scbs = ((t & 7) * 16) ^ ((srow & 7) << 4);
  const char* Ag = (const char*)A + (size_t)(bm * 256 + srow) * 2048 + scbs;
  const char* Bg = (const char*)Bw + (size_t)(bn * 128 + srow) * 2048 + scbs;
  char* lw = LB + w * 1024;  // wave-uniform dest base

#define STAGE_A(d, KT)                                                     \
  {                                                                        \
    GL16(Ag + (KT) * 128, lw + (d) * 32768);                               \
    GL16(Ag + (KT) * 128 + (size_t)64 * 2048, lw + (d) * 32768 + 8192);    \
    GL16(Ag + (KT) * 128 + (size_t)128 * 2048, lw + (d) * 32768 + 16384);  \
    GL16(Ag + (KT) * 128 + (size_t)192 * 2048, lw + (d) * 32768 + 24576);  \
  }
#define STAGE_B(d, KT)                                                     \
  {                                                                        \
    GL16(Bg + (KT) * 128, lw + 65536 + (d) * 16384);                       \
    GL16(Bg + (KT) * 128 + (size_t)64 * 2048, lw + 65536 + (d) * 16384 + 8192); \
  }

  // fragment read cols (swizzled; row&7 == lr&7 for all fragment rows)
  const int sw = (lr & 7) << 4;
  const int c0 = (lg * 16) ^ sw;         // kk=0
  const int c1 = (64 + lg * 16) ^ sw;    // kk=1

  f32x4 acc[4][4] = {};

  STAGE_A(0, 0) STAGE_B(0, 0) STAGE_A(1, 1)
  asm volatile("s_waitcnt vmcnt(4)" ::: "memory");
  __builtin_amdgcn_s_barrier();
  __builtin_amdgcn_sched_barrier(0);

#define KTILE(KT, X)                                                          \
  {                                                                           \
    const char* Ab = LB + (X) * 32768;                                        \
    const char* Bb = LB + 65536 + (X) * 16384;                                \
    bf16x8 af[4][2], bf[2][2];                                                \
    _Pragma("unroll") for (int m = 0; m < 4; ++m) {                           \
      const int ar = (wr * 64 + m * 16 + lr) * 128;                           \
      af[m][0] = *(const bf16x8*)(Ab + ar + c0);                              \
      af[m][1] = *(const bf16x8*)(Ab + ar + c1);                              \
    }                                                                         \
    _Pragma("unroll") for (int n = 0; n < 2; ++n) {                           \
      const int br = (wc * 64 + n * 16 + lr) * 128;                           \
      bf[n][0] = *(const bf16x8*)(Bb + br + c0);                              \
      bf[n][1] = *(const bf16x8*)(Bb + br + c1);                              \
    }                                                                         \
    if ((KT) + 1 < nk) STAGE_B((X) ^ 1, (KT) + 1)                             \
    __builtin_amdgcn_s_barrier();                                             \
    __builtin_amdgcn_sched_barrier(0);                                        \
    __builtin_amdgcn_s_setprio(1);                                            \
    _Pragma("unroll") for (int m = 0; m < 4; ++m)                             \
      _Pragma("unroll") for (int kk = 0; kk < 2; ++kk) {                      \
        acc[m][0] = MFMA16(af[m][kk], bf[0][kk], acc[m][0]);                  \
        acc[m][1] = MFMA16(af[m][kk], bf[1][kk], acc[m][1]);                  \
      }                                                                       \
    __builtin_amdgcn_s_setprio(0);                                            \
    __builtin_amdgcn_s_barrier();                                             \
    __builtin_amdgcn_sched_barrier(0);                                        \
    _Pragma("unroll") for (int n = 0; n < 2; ++n) {                           \
      const int br = (wc * 64 + (n + 2) * 16 + lr) * 128;                     \
      bf[n][0] = *(const bf16x8*)(Bb + br + c0);                              \
      bf[n][1] = *(const bf16x8*)(Bb + br + c1);                              \
    }                                                                         \
    if ((KT) + 2 < nk) STAGE_A(X, (KT) + 2)                                   \
    __builtin_amdgcn_s_barrier();                                             \
    __builtin_amdgcn_sched_barrier(0);                                        \
    __builtin_amdgcn_s_setprio(1);                                            \
    _Pragma("unroll") for (int m = 0; m < 4; ++m)                             \
      _Pragma("unroll") for (int kk = 0; kk < 2; ++kk) {                      \
        acc[m][2] = MFMA16(af[m][kk], bf[0][kk], acc[m][2]);                  \
        acc[m][3] = MFMA16(af[m][kk], bf[1][kk], acc[m][3]);                  \
      }                                                                       \
    __builtin_amdgcn_s_setprio(0);                                            \
    if ((KT) + 2 < nk)                                                        \
      asm volatile("s_waitcnt vmcnt(4)" ::: "memory");                        \
    else                                                                      \
      asm volatile("s_waitcnt vmcnt(0)" ::: "memory");                        \
    __builtin_amdgcn_s_barrier();                                             \
    __builtin_amdgcn_sched_barrier(0);                                        \
  }

  for (int kt = 0; kt < nk; kt += 2) {
    KTILE(kt, 0)
    KTILE(kt + 1, 1)
  }

  // ---------------- epilogue ----------------
  if (MODE == 3) {
    float* outp = (float*)Cout;
#pragma unroll
    for (int m = 0; m < 4; ++m)
#pragma unroll
      for (int n = 0; n < 4; ++n)
#pragma unroll
        for (int e = 0; e < 4; ++e) {
          const int grow = bm * 256 + wr * 64 + m * 16 + lg * 4 + e;
          const int gcol = bn * 128 + wc * 64 + n * 16 + lr;
          outp[(size_t)grow * 1024 + gcol] = acc[m][n][e];
        }
  } else {
    const int seg = bn >> 3;  // 0=Q 1=K 2=V
    const int bnn = bn & 7;
    if (seg < 2) {
      const int h = bnn * 2 + wc;
      __bf16* base = (__bf16*)Cout + (size_t)seg * 8388608;
#pragma unroll
      for (int m = 0; m < 4; ++m)
#pragma unroll
        for (int e = 0; e < 4; ++e) {
          const int grow = bm * 256 + wr * 64 + m * 16 + lg * 4 + e;
          const int pos = tpos[grow];
          const int b = grow >> 11, s = grow & 2047;
          __bf16* orow = &base[(((size_t)(b * 16 + h)) * 2048 + s) * 64];
#pragma unroll
          for (int j = 0; j < 2; ++j) {
            const int dd = j * 16 + lr;
            const float c = ct[pos * 32 + dd], sn = st[pos * 32 + dd];
            float x1 = acc[m][j][e], x2 = acc[m][j + 2][e];
            float o1 = x1 * c - x2 * sn;
            float o2 = x2 * c + x1 * sn;
            if (seg == 0) { o1 *= QSCALE; o2 *= QSCALE; }
            orow[dd] = (__bf16)o1;
            orow[dd + 32] = (__bf16)o2;
          }
        }
    } else {
      __bf16* base = (__bf16*)Cout + 16777216;
#pragma unroll
      for (int m = 0; m < 4; ++m)
#pragma unroll
        for (int n = 0; n < 4; ++n) {
          const int grow0 = bm * 256 + wr * 64 + m * 16 + lg * 4;
          const int gcs = bnn * 128 + wc * 64 + n * 16 + lr;
          const int b = grow0 >> 11, s = grow0 & 2047;
          const int h = gcs >> 6, d = gcs & 63;
          bf16x4 vv;
#pragma unroll
          for (int e = 0; e < 4; ++e) vv[e] = (__bf16)acc[m][n][e];
          *(bf16x4*)&base[(((size_t)(b * 16 + h)) * 64 + d) * 2048 + s] = vv;
        }
    }
  }
}

// ------------------------- paired-causal flash attention -------------------
static __device__ __forceinline__ u32 pk2(float a, float b) {
  union { __bf16 h[2]; u32 w; } u;
  u.h[0] = (__bf16)a; u.h[1] = (__bf16)b;
  return u.w;
}

#define PACK_FRAG(SRC, OFF, OUT)                                            \
  {                                                                         \
    u32 c01 = pk2(SRC[(OFF) + 0], SRC[(OFF) + 1]);                          \
    u32 c23 = pk2(SRC[(OFF) + 2], SRC[(OFF) + 3]);                          \
    u32 c45 = pk2(SRC[(OFF) + 4], SRC[(OFF) + 5]);                          \
    u32 c67 = pk2(SRC[(OFF) + 6], SRC[(OFF) + 7]);                          \
    u32 x1_ = (u32)__shfl_xor((int)(hi ? c01 : c45), 32);                   \
    u32 x2_ = (u32)__shfl_xor((int)(hi ? c23 : c67), 32);                   \
    union { u32 w[4]; bf16x8 v; } fu_;                                      \
    fu_.w[0] = hi ? x1_ : c01;                                              \
    fu_.w[1] = hi ? x2_ : c23;                                              \
    fu_.w[2] = hi ? c45 : x1_;                                              \
    fu_.w[3] = hi ? c67 : x2_;                                              \
    OUT = fu_.v;                                                            \
  }

#define KOFF(row, cb) ((row) * 128 + ((cb) ^ (((row) & 7) << 4)))
#define VOFF(row, cb) ((row) * 256 + ((cb) ^ (((row) & 7) << 4)))

static __device__ __forceinline__ void qkt(const char* kcs, const bf16x8* qf,
                                           int lq, int hi, f32x16& s0, f32x16& s1) {
  s0 = (f32x16){}; s1 = (f32x16){};
#pragma unroll
  for (int ds = 0; ds < 4; ++ds) {
    bf16x8 kf = *(const bf16x8*)(kcs + KOFF(lq, ds * 32 + hi * 16));
    s0 = MFMA32(kf, qf[ds], s0);
  }
#pragma unroll
  for (int ds = 0; ds < 4; ++ds) {
    bf16x8 kf = *(const bf16x8*)(kcs + KOFF(32 + lq, ds * 32 + hi * 16));
    s1 = MFMA32(kf, qf[ds], s1);
  }
}

static __device__ __forceinline__ float maskmax(f32x16& s0, f32x16& s1, int k0,
                                                int q0w, int qrow, int hi) {
  if (k0 + 63 > q0w) {
#pragma unroll
    for (int r = 0; r < 16; ++r) {
      int kl_ = k0 + (r & 3) + 8 * (r >> 2) + 4 * hi;
      s0[r] = (kl_ > qrow) ? -1e30f : s0[r];
      s1[r] = (kl_ + 32 > qrow) ? -1e30f : s1[r];
    }
  }
  float m[8];
#pragma unroll
  for (int r = 0; r < 8; ++r)
    m[r] = fmaxf(fmaxf(s0[r], s0[r + 8]), fmaxf(s1[r], s1[r + 8]));
#pragma unroll
  for (int r = 0; r < 4; ++r) m[r] = fmaxf(m[r], m[r + 4]);
  float pm = fmaxf(fmaxf(m[0], m[1]), fmaxf(m[2], m[3]));
  return fmaxf(pm, __shfl_xor(pm, 32));
}

static __device__ __forceinline__ void smpack(f32x16& s0, f32x16& s1, float pmax,
                                              float& mrun, float& lrun,
                                              f32x16& o0, f32x16& o1,
                                              bf16x8* pa, int hi) {
  if (!__all(pmax <= mrun + 8.0f)) {
    float nm = fmaxf(mrun, pmax);
    float corr = EXP2(mrun - nm);
    mrun = nm;
    lrun *= corr;
#pragma unroll
    for (int r = 0; r < 16; ++r) { o0[r] *= corr; o1[r] *= corr; }
  }
  float rsp0 = 0.f, rsp1 = 0.f, rsp2 = 0.f, rsp3 = 0.f;
#pragma unroll
  for (int r = 0; r < 4; ++r) {
    float e0 = EXP2(s0[r] - mrun), e1 = EXP2(s0[r + 4] - mrun);
    float e2 = EXP2(s0[r + 8] - mrun), e3 = EXP2(s0[r + 12] - mrun);
    s0[r] = e0; s0[r + 4] = e1; s0[r + 8] = e2; s0[r + 12] = e3;
    rsp0 += e0; rsp1 += e1; rsp2 += e2; rsp3 += e3;
  }
#pragma unroll
  for (int r = 0; r < 4; ++r) {
    float e0 = EXP2(s1[r] - mrun), e1 = EXP2(s1[r + 4] - mrun);
    float e2 = EXP2(s1[r + 8] - mrun), e3 = EXP2(s1[r + 12] - mrun);
    s1[r] = e0; s1[r + 4] = e1; s1[r + 8] = e2; s1[r + 12] = e3;
    rsp0 += e0; rsp1 += e1; rsp2 += e2; rsp3 += e3;
  }
  float rs = (rsp0 + rsp1) + (rsp2 + rsp3);
  rs += __shfl_xor(rs, 32);
  lrun += rs;
  PACK_FRAG(s0, 0, pa[0])
  PACK_FRAG(s0, 8, pa[1])
  PACK_FRAG(s1, 0, pa[2])
  PACK_FRAG(s1, 8, pa[3])
}

static __device__ __forceinline__ void pv(const char* vc, int vcb0, int lq, int hi,
                                          const bf16x8* pa, f32x16& o0, f32x16& o1) {
#pragma unroll
  for (int fi = 0; fi < 4; ++fi) {
    bf16x8 vf = *(const bf16x8*)(vc + VOFF(lq, vcb0 + fi * 32 + hi * 16));
    o0 = MFMA32(vf, pa[fi], o0);
  }
#pragma unroll
  for (int fi = 0; fi < 4; ++fi) {
    bf16x8 vf = *(const bf16x8*)(vc + VOFF(32 + lq, vcb0 + fi * 32 + hi * 16));
    o1 = MFMA32(vf, pa[fi], o1);
  }
}

__global__ __launch_bounds__(512) void attn_fwd(const __bf16* __restrict__ Q,
                                                const __bf16* __restrict__ Kb,
                                                const __bf16* __restrict__ VTg,
                                                __bf16* __restrict__ O) {
  __shared__ __align__(16) __bf16 Ks[2][128 * 64];
  __shared__ __align__(16) __bf16 Vs[2][64 * 128];
  const int t = threadIdx.x, w = t >> 6, l = t & 63;
  const int lq = l & 31, hi = l >> 5;
  const int id = blockIdx.x;
  const int bh = (id & 7) + 8 * (id >> 5);
  const int p = (id >> 3) & 3;
  const int qbA = p, qbB = 7 - p;
  const int qA0w = qbA * 256 + w * 32, qB0w = qbB * 256 + w * 32;
  const int qArow = qA0w + lq, qBrow = qB0w + lq;
  const size_t kbaseB = (size_t)bh * (2048 * 64 * 2);
  const size_t vbaseB = (size_t)bh * (64 * 2048 * 2);

  const int srow = t >> 3;
  const int scolb = ((t & 7) * 16) ^ ((srow & 7) << 4);
  const int vrow = t >> 4;
  const int vcolb = ((t & 15) * 16) ^ ((vrow & 7) << 4);
  const char* kgp = (const char*)Kb + kbaseB + (size_t)srow * 128 + scolb;
  const char* vgp = (const char*)VTg + vbaseB + (size_t)vrow * 4096 + vcolb;
  char* kl = (char*)&Ks[0][0] + w * 1024;
  char* vl = (char*)&Vs[0][0] + w * 1024;

#define STAGE(bi, KT)                                                      \
  {                                                                        \
    GL16(kgp + (size_t)(KT) * 16384, kl + (bi) * 16384);                   \
    GL16(kgp + (size_t)(KT) * 16384 + 64 * 128, kl + (bi) * 16384 + 8192); \
    GL16(vgp + (size_t)(KT) * 256, vl + (bi) * 16384);                     \
    GL16(vgp + (size_t)(KT) * 256 + (size_t)32 * 4096,                     \
         vl + (bi) * 16384 + 8192);                                        \
  }

  const size_t qbase = (size_t)bh * (2048 * 64);
  bf16x8 qfA[4], qfB[4];
#pragma unroll
  for (int ds = 0; ds < 4; ++ds) {
    qfA[ds] = *(const bf16x8*)&Q[qbase + (size_t)qArow * 64 + ds * 16 + hi * 8];
    qfB[ds] = *(const bf16x8*)&Q[qbase + (size_t)qBrow * 64 + ds * 16 + hi * 8];
  }

  f32x16 oA0 = {}, oA1 = {}, oB0 = {}, oB1 = {};
  float mA = -1e30f, lA = 0.0f, mB = -1e30f, lB = 0.0f;

  const int nkt = 2 * qbB + 2;
  STAGE(0, 0)
  int cur = 0;
  for (int kt = 0; kt < nkt; ++kt) {
    if (kt + 1 < nkt) {
      STAGE(cur ^ 1, kt + 1)
      asm volatile("s_waitcnt vmcnt(4)" ::: "memory");
    } else {
      asm volatile("s_waitcnt vmcnt(0)" ::: "memory");
    }
    __builtin_amdgcn_s_barrier();
    __builtin_amdgcn_sched_barrier(0);
    const char* kc = (const char*)&Ks[cur][0];
    const char* vc = (const char*)&Vs[cur][0];

#pragma unroll
    for (int sub = 0; sub < 2; ++sub) {
      const int k0 = kt * 128 + sub * 64;
      const char* kcs = kc + sub * 8192;
      const int vcb0 = sub * 128;
      if (k0 > qB0w + 31) continue;
      const bool doA = (k0 <= qA0w + 31);

      f32x16 sB0, sB1, sA0, sA1;
      __builtin_amdgcn_s_setprio(1);
      qkt(kcs, qfB, lq, hi, sB0, sB1);
      if (doA) qkt(kcs, qfA, lq, hi, sA0, sA1);
      __builtin_amdgcn_s_setprio(0);

      float pmB = maskmax(sB0, sB1, k0, qB0w, qBrow, hi);
      bf16x8 paB[4], paA[4];
      if (doA) {
        float pmA = maskmax(sA0, sA1, k0, qA0w, qArow, hi);
        smpack(sB0, sB1, pmB, mB, lB, oB0, oB1, paB, hi);
        smpack(sA0, sA1, pmA, mA, lA, oA0, oA1, paA, hi);
        __builtin_amdgcn_s_setprio(1);
        pv(vc, vcb0, lq, hi, paB, oB0, oB1);
        pv(vc, vcb0, lq, hi, paA, oA0, oA1);
        __builtin_amdgcn_s_setprio(0);
      } else {
        smpack(sB0, sB1, pmB, mB, lB, oB0, oB1, paB, hi);
        __builtin_amdgcn_s_setprio(1);
        pv(vc, vcb0, lq, hi, paB, oB0, oB1);
        __builtin_amdgcn_s_setprio(0);
      }
    }
    __builtin_amdgcn_s_barrier();
    cur ^= 1;
  }

  const int b = bh >> 4, h = bh & 15;
  {
    float inv = 1.0f / lA;
    __bf16* orow = O + ((size_t)(b * 2048 + qArow)) * 1024 + h * 64;
#pragma unroll
    for (int rq = 0; rq < 4; ++rq) {
      bf16x4 v0, v1;
#pragma unroll
      for (int e = 0; e < 4; ++e) {
        v0[e] = (__bf16)(oA0[rq * 4 + e] * inv);
        v1[e] = (__bf16)(oA1[rq * 4 + e] * inv);
      }
      *(bf16x4*)&orow[8 * rq + 4 * hi] = v0;
      *(bf16x4*)&orow[32 + 8 * rq + 4 * hi] = v1;
    }
  }
  {
    float inv = 1.0f / lB;
    __bf16* orow = O + ((size_t)(b * 2048 + qBrow)) * 1024 + h * 64;
#pragma unroll
    for (int rq = 0; rq < 4; ++rq) {
      bf16x4 v0, v1;
#pragma unroll
      for (int e = 0; e < 4; ++e) {
        v0[e] = (__bf16)(oB0[rq * 4 + e] * inv);
        v1[e] = (__bf16)(oB1[rq * 4 + e] * inv);
      }
      *(bf16x4*)&orow[8 * rq + 4 * hi] = v0;
      *(bf16x4*)&orow[32 + 8 * rq + 4 * hi] = v1;
    }
  }
}

// ---------------------------------------------------------------------------
extern "C" void kernel_launch(void* const* d_in, const int* in_sizes, int n_in,
                              void* d_out, int out_size, void* d_ws, size_t ws_size,
                              hipStream_t stream) {
  const float* x = (const float*)d_in[0];
  const float* wq = (const float*)d_in[1];
  const float* wk = (const float*)d_in[2];
  const float* wv = (const float*)d_in[3];
  const float* wo = (const float*)d_in[4];
  const int* tpos = (const int*)d_in[5];
  float* out = (float*)d_out;

  const size_t SZ_X = 8192u * 1024u * 2u;
  const size_t SZ_W = 1024u * 1024u * 2u;
  const size_t SZ_T = 2048u * 32u * 4u;
  const size_t NEED = SZ_X * 4 + SZ_W * 4 + SZ_T * 2;
  if (ws_size < NEED) return;

  char* p = (char*)d_ws;
  __bf16* xb  = (__bf16*)p; p += SZ_X;   // reused as attention output (AO)
  __bf16* wqb = (__bf16*)p; p += SZ_W;   // 4 weights contiguous (wq|wk|wv|wo)
  __bf16* wkb = (__bf16*)p; p += SZ_W;
  __bf16* wvb = (__bf16*)p; p += SZ_W;
  __bf16* wob = (__bf16*)p; p += SZ_W;
  __bf16* Qb  = (__bf16*)p; p += SZ_X;   // Q | K | V^T contiguous
  __bf16* Kbf = (__bf16*)p; p += SZ_X;
  __bf16* VTg = (__bf16*)p; p += SZ_X;
  float* ct = (float*)p; p += SZ_T;
  float* st = (float*)p; p += SZ_T;
  __bf16* AOb = xb;
  (void)wkb; (void)wvb;

  cvt_kernel<<<8192, 256, 0, stream>>>(x, xb, 2097152);
  cvt_w4<<<4096, 256, 0, stream>>>(wq, wk, wv, wo, wqb);
  rope_table<<<256, 256, 0, stream>>>(ct, st);

  // fused QKV: B = wq|wk|wv rows (contiguous), N=3072; grid 768 = 3/CU
  gemm8<4><<<768, 512, 0, stream>>>(xb, wqb, (void*)Qb, tpos, ct, st);

  attn_fwd<<<256, 512, 0, stream>>>(Qb, Kbf, VTg, AOb);

  // out projection: N=1024; grid 256 = 1/CU
  gemm8<3><<<256, 512, 0, stream>>>(AOb, wob, (void*)out, tpos, ct, st);
}

// Round 8
// 172.967 us; speedup vs baseline: 3.2426x; 1.0870x over previous
//
#include <hip/hip_runtime.h>

// ---------------------------------------------------------------------------
// MultiHeadSelfAttentionWithRoPE: B=4, S=2048, D_MODEL=1024, H=16, D_K=64
// cvt->bf16 | phase-split 256x128 QKV GEMM (RoPE fused; V transposed;
// A-panel XCD-pinned block map) | paired-causal 8-warp flash attn |
// phase-split out GEMM
// ---------------------------------------------------------------------------

typedef float f32x4 __attribute__((ext_vector_type(4)));
typedef float f32x16 __attribute__((ext_vector_type(16)));
typedef __bf16 bf16x8 __attribute__((ext_vector_type(8)));
typedef __bf16 bf16x4 __attribute__((ext_vector_type(4)));
typedef unsigned int u32;

#define MFMA16(a, b, c) __builtin_amdgcn_mfma_f32_16x16x32_bf16((a), (b), (c), 0, 0, 0)
#define MFMA32(a, b, c) __builtin_amdgcn_mfma_f32_32x32x16_bf16((a), (b), (c), 0, 0, 0)

#define GL16(gp, lp)                                                        \
  __builtin_amdgcn_global_load_lds(                                         \
      (const __attribute__((address_space(1))) void*)(gp),                  \
      (__attribute__((address_space(3))) void*)(lp), 16, 0, 0)

#define EXP2(x) __builtin_amdgcn_exp2f(x)
#define QSCALE 0.18033688011112042f

// ------------------------------- cvt f32 -> bf16 ---------------------------
__global__ void cvt_kernel(const float* __restrict__ src, __bf16* __restrict__ dst, int n4) {
  int i = blockIdx.x * blockDim.x + threadIdx.x;
  if (i < n4) {
    float4 v = ((const float4*)src)[i];
    bf16x4 o;
    o[0] = (__bf16)v.x; o[1] = (__bf16)v.y; o[2] = (__bf16)v.z; o[3] = (__bf16)v.w;
    ((bf16x4*)dst)[i] = o;
  }
}

__global__ void cvt_w4(const float* __restrict__ wq, const float* __restrict__ wk,
                       const float* __restrict__ wv, const float* __restrict__ wo,
                       __bf16* __restrict__ dst) {
  int i = blockIdx.x * 256 + threadIdx.x;
  int sel = i >> 18;
  const float* src = sel == 0 ? wq : sel == 1 ? wk : sel == 2 ? wv : wo;
  int j = i & 262143;
  float4 v = ((const float4*)src)[j];
  bf16x4 o;
  o[0] = (__bf16)v.x; o[1] = (__bf16)v.y; o[2] = (__bf16)v.z; o[3] = (__bf16)v.w;
  ((bf16x4*)dst)[i] = o;
}

// ------------------------------- RoPE table --------------------------------
__global__ void rope_table(float* __restrict__ ct, float* __restrict__ st) {
  int i = blockIdx.x * 256 + threadIdx.x;
  int pos = i >> 5, f = i & 31;
  float inv = powf(10000.0f, -(float)f * (1.0f / 32.0f));
  float a = (float)pos * inv;
  ct[i] = cosf(a);
  st[i] = sinf(a);
}

// --------------- phase-split GEMM: C = A(8192xK) * B(NxK)^T ----------------
// BM=256, BN=128, BK=64, 512 thr = 8 waves (4M x 2N), per-wave 64x64.
// Block map: XCD k owns bm in {4k..4k+3} (A panels pinned in its L2, 2MB),
// bn sweeps -> A fetched ~once per XCD, B streams.
// MODE 4: fused QKV (N=3072): seg 0=Q(RoPE+QSCALE) 1=K(RoPE) 2=V^T
// MODE 3: out f32 (N=1024)
template <int MODE>
__global__ __launch_bounds__(512, 2) void gemm8(const __bf16* __restrict__ A,
                                                const __bf16* __restrict__ Bw,
                                                void* __restrict__ Cout,
                                                const int* __restrict__ tpos,
                                                const float* __restrict__ ct,
                                                const float* __restrict__ st) {
  __shared__ __align__(16) char LB[98304];
  const int nk = 16;  // K=1024 / BK=64
  const int t = threadIdx.x, w = t >> 6, l = t & 63;
  const int lr = l & 15, lg = l >> 4;
  const int wr = w >> 1, wc = w & 1;
  // A-panel XCD-pinned map (round-robin id->XCD assumption, id&7 = xcd)
  const int id = blockIdx.x;
  const int xcd = id & 7, i = id >> 3;
  const int bm = xcd * 4 + (i & 3);  // 4 panels per XCD, L2-resident
  const int bn = i >> 2;             // sweeps 0..23 (MODE4) / 0..7 (MODE3)

  // staging: thread t covers linear LDS bytes t*16 (+8192) per unit;
  // global source col pre-swizzled (inverse of read swizzle)
  const int srow = t >> 3;
  const int scbs = ((t & 7) * 16) ^ ((srow & 7) << 4);
  const char* Ag = (const char*)A + (size_t)(bm * 256 + srow) * 2048 + scbs;
  const char* Bg = (const char*)Bw + (size_t)(bn * 128 + srow) * 2048 + scbs;
  char* lw = LB + w * 1024;  // wave-uniform dest base

#define STAGE_A(d, KT)                                                     \
  {                                                                        \
    GL16(Ag + (KT) * 128, lw + (d) * 32768);                               \
    GL16(Ag + (KT) * 128 + (size_t)64 * 2048, lw + (d) * 32768 + 8192);    \
    GL16(Ag + (KT) * 128 + (size_t)128 * 2048, lw + (d) * 32768 + 16384);  \
    GL16(Ag + (KT) * 128 + (size_t)192 * 2048, lw + (d) * 32768 + 24576);  \
  }
#define STAGE_B(d, KT)                                                     \
  {                                                                        \
    GL16(Bg + (KT) * 128, lw + 65536 + (d) * 16384);                       \
    GL16(Bg + (KT) * 128 + (size_t)64 * 2048, lw + 65536 + (d) * 16384 + 8192); \
  }

  // fragment read cols (swizzled; row&7 == lr&7 for all fragment rows)
  const int sw = (lr & 7) << 4;
  const int c0 = (lg * 16) ^ sw;         // kk=0
  const int c1 = (64 + lg * 16) ^ sw;    // kk=1

  f32x4 acc[4][4] = {};

  STAGE_A(0, 0) STAGE_B(0, 0) STAGE_A(1, 1)
  asm volatile("s_waitcnt vmcnt(4)" ::: "memory");
  __builtin_amdgcn_s_barrier();
  __builtin_amdgcn_sched_barrier(0);

#define KTILE(KT, X)                                                          \
  {                                                                           \
    const char* Ab = LB + (X) * 32768;                                        \
    const char* Bb = LB + 65536 + (X) * 16384;                                \
    bf16x8 af[4][2], bf[2][2];                                                \
    _Pragma("unroll") for (int m = 0; m < 4; ++m) {                           \
      const int ar = (wr * 64 + m * 16 + lr) * 128;                           \
      af[m][0] = *(const bf16x8*)(Ab + ar + c0);                              \
      af[m][1] = *(const bf16x8*)(Ab + ar + c1);                              \
    }                                                                         \
    _Pragma("unroll") for (int n = 0; n < 2; ++n) {                           \
      const int br = (wc * 64 + n * 16 + lr) * 128;                           \
      bf[n][0] = *(const bf16x8*)(Bb + br + c0);                              \
      bf[n][1] = *(const bf16x8*)(Bb + br + c1);                              \
    }                                                                         \
    if ((KT) + 1 < nk) STAGE_B((X) ^ 1, (KT) + 1)                             \
    __builtin_amdgcn_s_barrier();                                             \
    __builtin_amdgcn_sched_barrier(0);                                        \
    __builtin_amdgcn_s_setprio(1);                                            \
    _Pragma("unroll") for (int m = 0; m < 4; ++m)                             \
      _Pragma("unroll") for (int kk = 0; kk < 2; ++kk) {                      \
        acc[m][0] = MFMA16(af[m][kk], bf[0][kk], acc[m][0]);                  \
        acc[m][1] = MFMA16(af[m][kk], bf[1][kk], acc[m][1]);                  \
      }                                                                       \
    __builtin_amdgcn_s_setprio(0);                                            \
    __builtin_amdgcn_s_barrier();                                             \
    __builtin_amdgcn_sched_barrier(0);                                        \
    _Pragma("unroll") for (int n = 0; n < 2; ++n) {                           \
      const int br = (wc * 64 + (n + 2) * 16 + lr) * 128;                     \
      bf[n][0] = *(const bf16x8*)(Bb + br + c0);                              \
      bf[n][1] = *(const bf16x8*)(Bb + br + c1);                              \
    }                                                                         \
    if ((KT) + 2 < nk) STAGE_A(X, (KT) + 2)                                   \
    __builtin_amdgcn_s_barrier();                                             \
    __builtin_amdgcn_sched_barrier(0);                                        \
    __builtin_amdgcn_s_setprio(1);                                            \
    _Pragma("unroll") for (int m = 0; m < 4; ++m)                             \
      _Pragma("unroll") for (int kk = 0; kk < 2; ++kk) {                      \
        acc[m][2] = MFMA16(af[m][kk], bf[0][kk], acc[m][2]);                  \
        acc[m][3] = MFMA16(af[m][kk], bf[1][kk], acc[m][3]);                  \
      }                                                                       \
    __builtin_amdgcn_s_setprio(0);                                            \
    if ((KT) + 2 < nk)                                                        \
      asm volatile("s_waitcnt vmcnt(4)" ::: "memory");                        \
    else                                                                      \
      asm volatile("s_waitcnt vmcnt(0)" ::: "memory");                        \
    __builtin_amdgcn_s_barrier();                                             \
    __builtin_amdgcn_sched_barrier(0);                                        \
  }

  for (int kt = 0; kt < nk; kt += 2) {
    KTILE(kt, 0)
    KTILE(kt + 1, 1)
  }

  // ---------------- epilogue ----------------
  if (MODE == 3) {
    float* outp = (float*)Cout;
#pragma unroll
    for (int m = 0; m < 4; ++m)
#pragma unroll
      for (int n = 0; n < 4; ++n)
#pragma unroll
        for (int e = 0; e < 4; ++e) {
          const int grow = bm * 256 + wr * 64 + m * 16 + lg * 4 + e;
          const int gcol = bn * 128 + wc * 64 + n * 16 + lr;
          outp[(size_t)grow * 1024 + gcol] = acc[m][n][e];
        }
  } else {
    const int seg = bn >> 3;  // 0=Q 1=K 2=V
    const int bnn = bn & 7;
    if (seg < 2) {
      const int h = bnn * 2 + wc;
      __bf16* base = (__bf16*)Cout + (size_t)seg * 8388608;
#pragma unroll
      for (int m = 0; m < 4; ++m)
#pragma unroll
        for (int e = 0; e < 4; ++e) {
          const int grow = bm * 256 + wr * 64 + m * 16 + lg * 4 + e;
          const int pos = tpos[grow];
          const int b = grow >> 11, s = grow & 2047;
          __bf16* orow = &base[(((size_t)(b * 16 + h)) * 2048 + s) * 64];
#pragma unroll
          for (int j = 0; j < 2; ++j) {
            const int dd = j * 16 + lr;
            const float c = ct[pos * 32 + dd], sn = st[pos * 32 + dd];
            float x1 = acc[m][j][e], x2 = acc[m][j + 2][e];
            float o1 = x1 * c - x2 * sn;
            float o2 = x2 * c + x1 * sn;
            if (seg == 0) { o1 *= QSCALE; o2 *= QSCALE; }
            orow[dd] = (__bf16)o1;
            orow[dd + 32] = (__bf16)o2;
          }
        }
    } else {
      __bf16* base = (__bf16*)Cout + 16777216;
#pragma unroll
      for (int m = 0; m < 4; ++m)
#pragma unroll
        for (int n = 0; n < 4; ++n) {
          const int grow0 = bm * 256 + wr * 64 + m * 16 + lg * 4;
          const int gcs = bnn * 128 + wc * 64 + n * 16 + lr;
          const int b = grow0 >> 11, s = grow0 & 2047;
          const int h = gcs >> 6, d = gcs & 63;
          bf16x4 vv;
#pragma unroll
          for (int e = 0; e < 4; ++e) vv[e] = (__bf16)acc[m][n][e];
          *(bf16x4*)&base[(((size_t)(b * 16 + h)) * 64 + d) * 2048 + s] = vv;
        }
    }
  }
}

// ------------------------- paired-causal flash attention -------------------
static __device__ __forceinline__ u32 pk2(float a, float b) {
  union { __bf16 h[2]; u32 w; } u;
  u.h[0] = (__bf16)a; u.h[1] = (__bf16)b;
  return u.w;
}

#define PACK_FRAG(SRC, OFF, OUT)                                            \
  {                                                                         \
    u32 c01 = pk2(SRC[(OFF) + 0], SRC[(OFF) + 1]);                          \
    u32 c23 = pk2(SRC[(OFF) + 2], SRC[(OFF) + 3]);                          \
    u32 c45 = pk2(SRC[(OFF) + 4], SRC[(OFF) + 5]);                          \
    u32 c67 = pk2(SRC[(OFF) + 6], SRC[(OFF) + 7]);                          \
    u32 x1_ = (u32)__shfl_xor((int)(hi ? c01 : c45), 32);                   \
    u32 x2_ = (u32)__shfl_xor((int)(hi ? c23 : c67), 32);                   \
    union { u32 w[4]; bf16x8 v; } fu_;                                      \
    fu_.w[0] = hi ? x1_ : c01;                                              \
    fu_.w[1] = hi ? x2_ : c23;                                              \
    fu_.w[2] = hi ? c45 : x1_;                                              \
    fu_.w[3] = hi ? c67 : x2_;                                              \
    OUT = fu_.v;                                                            \
  }

#define KOFF(row, cb) ((row) * 128 + ((cb) ^ (((row) & 7) << 4)))
#define VOFF(row, cb) ((row) * 256 + ((cb) ^ (((row) & 7) << 4)))

static __device__ __forceinline__ void qkt(const char* kcs, const bf16x8* qf,
                                           int lq, int hi, f32x16& s0, f32x16& s1) {
  s0 = (f32x16){}; s1 = (f32x16){};
#pragma unroll
  for (int ds = 0; ds < 4; ++ds) {
    bf16x8 kf = *(const bf16x8*)(kcs + KOFF(lq, ds * 32 + hi * 16));
    s0 = MFMA32(kf, qf[ds], s0);
  }
#pragma unroll
  for (int ds = 0; ds < 4; ++ds) {
    bf16x8 kf = *(const bf16x8*)(kcs + KOFF(32 + lq, ds * 32 + hi * 16));
    s1 = MFMA32(kf, qf[ds], s1);
  }
}

static __device__ __forceinline__ float maskmax(f32x16& s0, f32x16& s1, int k0,
                                                int q0w, int qrow, int hi) {
  if (k0 + 63 > q0w) {
#pragma unroll
    for (int r = 0; r < 16; ++r) {
      int kl_ = k0 + (r & 3) + 8 * (r >> 2) + 4 * hi;
      s0[r] = (kl_ > qrow) ? -1e30f : s0[r];
      s1[r] = (kl_ + 32 > qrow) ? -1e30f : s1[r];
    }
  }
  float m[8];
#pragma unroll
  for (int r = 0; r < 8; ++r)
    m[r] = fmaxf(fmaxf(s0[r], s0[r + 8]), fmaxf(s1[r], s1[r + 8]));
#pragma unroll
  for (int r = 0; r < 4; ++r) m[r] = fmaxf(m[r], m[r + 4]);
  float pm = fmaxf(fmaxf(m[0], m[1]), fmaxf(m[2], m[3]));
  return fmaxf(pm, __shfl_xor(pm, 32));
}

static __device__ __forceinline__ void smpack(f32x16& s0, f32x16& s1, float pmax,
                                              float& mrun, float& lrun,
                                              f32x16& o0, f32x16& o1,
                                              bf16x8* pa, int hi) {
  if (!__all(pmax <= mrun + 8.0f)) {
    float nm = fmaxf(mrun, pmax);
    float corr = EXP2(mrun - nm);
    mrun = nm;
    lrun *= corr;
#pragma unroll
    for (int r = 0; r < 16; ++r) { o0[r] *= corr; o1[r] *= corr; }
  }
  float rsp0 = 0.f, rsp1 = 0.f, rsp2 = 0.f, rsp3 = 0.f;
#pragma unroll
  for (int r = 0; r < 4; ++r) {
    float e0 = EXP2(s0[r] - mrun), e1 = EXP2(s0[r + 4] - mrun);
    float e2 = EXP2(s0[r + 8] - mrun), e3 = EXP2(s0[r + 12] - mrun);
    s0[r] = e0; s0[r + 4] = e1; s0[r + 8] = e2; s0[r + 12] = e3;
    rsp0 += e0; rsp1 += e1; rsp2 += e2; rsp3 += e3;
  }
#pragma unroll
  for (int r = 0; r < 4; ++r) {
    float e0 = EXP2(s1[r] - mrun), e1 = EXP2(s1[r + 4] - mrun);
    float e2 = EXP2(s1[r + 8] - mrun), e3 = EXP2(s1[r + 12] - mrun);
    s1[r] = e0; s1[r + 4] = e1; s1[r + 8] = e2; s1[r + 12] = e3;
    rsp0 += e0; rsp1 += e1; rsp2 += e2; rsp3 += e3;
  }
  float rs = (rsp0 + rsp1) + (rsp2 + rsp3);
  rs += __shfl_xor(rs, 32);
  lrun += rs;
  PACK_FRAG(s0, 0, pa[0])
  PACK_FRAG(s0, 8, pa[1])
  PACK_FRAG(s1, 0, pa[2])
  PACK_FRAG(s1, 8, pa[3])
}

static __device__ __forceinline__ void pv(const char* vc, int vcb0, int lq, int hi,
                                          const bf16x8* pa, f32x16& o0, f32x16& o1) {
#pragma unroll
  for (int fi = 0; fi < 4; ++fi) {
    bf16x8 vf = *(const bf16x8*)(vc + VOFF(lq, vcb0 + fi * 32 + hi * 16));
    o0 = MFMA32(vf, pa[fi], o0);
  }
#pragma unroll
  for (int fi = 0; fi < 4; ++fi) {
    bf16x8 vf = *(const bf16x8*)(vc + VOFF(32 + lq, vcb0 + fi * 32 + hi * 16));
    o1 = MFMA32(vf, pa[fi], o1);
  }
}

__global__ __launch_bounds__(512) void attn_fwd(const __bf16* __restrict__ Q,
                                                const __bf16* __restrict__ Kb,
                                                const __bf16* __restrict__ VTg,
                                                __bf16* __restrict__ O) {
  __shared__ __align__(16) __bf16 Ks[2][128 * 64];
  __shared__ __align__(16) __bf16 Vs[2][64 * 128];
  const int t = threadIdx.x, w = t >> 6, l = t & 63;
  const int lq = l & 31, hi = l >> 5;
  const int id = blockIdx.x;
  const int bh = (id & 7) + 8 * (id >> 5);
  const int p = (id >> 3) & 3;
  const int qbA = p, qbB = 7 - p;
  const int qA0w = qbA * 256 + w * 32, qB0w = qbB * 256 + w * 32;
  const int qArow = qA0w + lq, qBrow = qB0w + lq;
  const size_t kbaseB = (size_t)bh * (2048 * 64 * 2);
  const size_t vbaseB = (size_t)bh * (64 * 2048 * 2);

  const int srow = t >> 3;
  const int scolb = ((t & 7) * 16) ^ ((srow & 7) << 4);
  const int vrow = t >> 4;
  const int vcolb = ((t & 15) * 16) ^ ((vrow & 7) << 4);
  const char* kgp = (const char*)Kb + kbaseB + (size_t)srow * 128 + scolb;
  const char* vgp = (const char*)VTg + vbaseB + (size_t)vrow * 4096 + vcolb;
  char* kl = (char*)&Ks[0][0] + w * 1024;
  char* vl = (char*)&Vs[0][0] + w * 1024;

#define STAGE(bi, KT)                                                      \
  {                                                                        \
    GL16(kgp + (size_t)(KT) * 16384, kl + (bi) * 16384);                   \
    GL16(kgp + (size_t)(KT) * 16384 + 64 * 128, kl + (bi) * 16384 + 8192); \
    GL16(vgp + (size_t)(KT) * 256, vl + (bi) * 16384);                     \
    GL16(vgp + (size_t)(KT) * 256 + (size_t)32 * 4096,                     \
         vl + (bi) * 16384 + 8192);                                        \
  }

  const size_t qbase = (size_t)bh * (2048 * 64);
  bf16x8 qfA[4], qfB[4];
#pragma unroll
  for (int ds = 0; ds < 4; ++ds) {
    qfA[ds] = *(const bf16x8*)&Q[qbase + (size_t)qArow * 64 + ds * 16 + hi * 8];
    qfB[ds] = *(const bf16x8*)&Q[qbase + (size_t)qBrow * 64 + ds * 16 + hi * 8];
  }

  f32x16 oA0 = {}, oA1 = {}, oB0 = {}, oB1 = {};
  float mA = -1e30f, lA = 0.0f, mB = -1e30f, lB = 0.0f;

  const int nkt = 2 * qbB + 2;
  STAGE(0, 0)
  int cur = 0;
  for (int kt = 0; kt < nkt; ++kt) {
    if (kt + 1 < nkt) {
      STAGE(cur ^ 1, kt + 1)
      asm volatile("s_waitcnt vmcnt(4)" ::: "memory");
    } else {
      asm volatile("s_waitcnt vmcnt(0)" ::: "memory");
    }
    __builtin_amdgcn_s_barrier();
    __builtin_amdgcn_sched_barrier(0);
    const char* kc = (const char*)&Ks[cur][0];
    const char* vc = (const char*)&Vs[cur][0];

#pragma unroll
    for (int sub = 0; sub < 2; ++sub) {
      const int k0 = kt * 128 + sub * 64;
      const char* kcs = kc + sub * 8192;
      const int vcb0 = sub * 128;
      if (k0 > qB0w + 31) continue;
      const bool doA = (k0 <= qA0w + 31);

      f32x16 sB0, sB1, sA0, sA1;
      __builtin_amdgcn_s_setprio(1);
      qkt(kcs, qfB, lq, hi, sB0, sB1);
      if (doA) qkt(kcs, qfA, lq, hi, sA0, sA1);
      __builtin_amdgcn_s_setprio(0);

      float pmB = maskmax(sB0, sB1, k0, qB0w, qBrow, hi);
      bf16x8 paB[4], paA[4];
      if (doA) {
        float pmA = maskmax(sA0, sA1, k0, qA0w, qArow, hi);
        smpack(sB0, sB1, pmB, mB, lB, oB0, oB1, paB, hi);
        smpack(sA0, sA1, pmA, mA, lA, oA0, oA1, paA, hi);
        __builtin_amdgcn_s_setprio(1);
        pv(vc, vcb0, lq, hi, paB, oB0, oB1);
        pv(vc, vcb0, lq, hi, paA, oA0, oA1);
        __builtin_amdgcn_s_setprio(0);
      } else {
        smpack(sB0, sB1, pmB, mB, lB, oB0, oB1, paB, hi);
        __builtin_amdgcn_s_setprio(1);
        pv(vc, vcb0, lq, hi, paB, oB0, oB1);
        __builtin_amdgcn_s_setprio(0);
      }
    }
    __builtin_amdgcn_s_barrier();
    cur ^= 1;
  }

  const int b = bh >> 4, h = bh & 15;
  {
    float inv = 1.0f / lA;
    __bf16* orow = O + ((size_t)(b * 2048 + qArow)) * 1024 + h * 64;
#pragma unroll
    for (int rq = 0; rq < 4; ++rq) {
      bf16x4 v0, v1;
#pragma unroll
      for (int e = 0; e < 4; ++e) {
        v0[e] = (__bf16)(oA0[rq * 4 + e] * inv);
        v1[e] = (__bf16)(oA1[rq * 4 + e] * inv);
      }
      *(bf16x4*)&orow[8 * rq + 4 * hi] = v0;
      *(bf16x4*)&orow[32 + 8 * rq + 4 * hi] = v1;
    }
  }
  {
    float inv = 1.0f / lB;
    __bf16* orow = O + ((size_t)(b * 2048 + qBrow)) * 1024 + h * 64;
#pragma unroll
    for (int rq = 0; rq < 4; ++rq) {
      bf16x4 v0, v1;
#pragma unroll
      for (int e = 0; e < 4; ++e) {
        v0[e] = (__bf16)(oB0[rq * 4 + e] * inv);
        v1[e] = (__bf16)(oB1[rq * 4 + e] * inv);
      }
      *(bf16x4*)&orow[8 * rq + 4 * hi] = v0;
      *(bf16x4*)&orow[32 + 8 * rq + 4 * hi] = v1;
    }
  }
}

// ---------------------------------------------------------------------------
extern "C" void kernel_launch(void* const* d_in, const int* in_sizes, int n_in,
                              void* d_out, int out_size, void* d_ws, size_t ws_size,
                              hipStream_t stream) {
  const float* x = (const float*)d_in[0];
  const float* wq = (const float*)d_in[1];
  const float* wk = (const float*)d_in[2];
  const float* wv = (const float*)d_in[3];
  const float* wo = (const float*)d_in[4];
  const int* tpos = (const int*)d_in[5];
  float* out = (float*)d_out;

  const size_t SZ_X = 8192u * 1024u * 2u;
  const size_t SZ_W = 1024u * 1024u * 2u;
  const size_t SZ_T = 2048u * 32u * 4u;
  const size_t NEED = SZ_X * 4 + SZ_W * 4 + SZ_T * 2;
  if (ws_size < NEED) return;

  char* p = (char*)d_ws;
  __bf16* xb  = (__bf16*)p; p += SZ_X;   // reused as attention output (AO)
  __bf16* wqb = (__bf16*)p; p += SZ_W;   // 4 weights contiguous (wq|wk|wv|wo)
  __bf16* wkb = (__bf16*)p; p += SZ_W;
  __bf16* wvb = (__bf16*)p; p += SZ_W;
  __bf16* wob = (__bf16*)p; p += SZ_W;
  __bf16* Qb  = (__bf16*)p; p += SZ_X;   // Q | K | V^T contiguous
  __bf16* Kbf = (__bf16*)p; p += SZ_X;
  __bf16* VTg = (__bf16*)p; p += SZ_X;
  float* ct = (float*)p; p += SZ_T;
  float* st = (float*)p; p += SZ_T;
  __bf16* AOb = xb;
  (void)wkb; (void)wvb;

  cvt_kernel<<<8192, 256, 0, stream>>>(x, xb, 2097152);
  cvt_w4<<<4096, 256, 0, stream>>>(wq, wk, wv, wo, wqb);
  rope_table<<<256, 256, 0, stream>>>(ct, st);

  // fused QKV: B = wq|wk|wv rows (contiguous), N=3072; grid 768 = 3/CU
  gemm8<4><<<768, 512, 0, stream>>>(xb, wqb, (void*)Qb, tpos, ct, st);

  attn_fwd<<<256, 512, 0, stream>>>(Qb, Kbf, VTg, AOb);

  // out projection: N=1024; grid 256 = 1/CU
  gemm8<3><<<256, 512, 0, stream>>>(AOb, wob, (void*)out, tpos, ct, st);
}

// Round 9
// 170.634 us; speedup vs baseline: 3.2870x; 1.0137x over previous
//
#include <hip/hip_runtime.h>

// ---------------------------------------------------------------------------
// MultiHeadSelfAttentionWithRoPE: B=4, S=2048, D_MODEL=1024, H=16, D_K=64
// cvt->bf16 | phase-split 256x128 QKV GEMM (RoPE fused; V transposed;
// A-panel XCD-pinned block map) | 16-warp paired-causal flash attn (4 waves/
// SIMD, one q-tile per warp) | phase-split out GEMM
// ---------------------------------------------------------------------------

typedef float f32x4 __attribute__((ext_vector_type(4)));
typedef float f32x16 __attribute__((ext_vector_type(16)));
typedef __bf16 bf16x8 __attribute__((ext_vector_type(8)));
typedef __bf16 bf16x4 __attribute__((ext_vector_type(4)));
typedef unsigned int u32;

#define MFMA16(a, b, c) __builtin_amdgcn_mfma_f32_16x16x32_bf16((a), (b), (c), 0, 0, 0)
#define MFMA32(a, b, c) __builtin_amdgcn_mfma_f32_32x32x16_bf16((a), (b), (c), 0, 0, 0)

#define GL16(gp, lp)                                                        \
  __builtin_amdgcn_global_load_lds(                                         \
      (const __attribute__((address_space(1))) void*)(gp),                  \
      (__attribute__((address_space(3))) void*)(lp), 16, 0, 0)

#define EXP2(x) __builtin_amdgcn_exp2f(x)
#define QSCALE 0.18033688011112042f

// ------------------------------- cvt f32 -> bf16 ---------------------------
__global__ void cvt_kernel(const float* __restrict__ src, __bf16* __restrict__ dst, int n4) {
  int i = blockIdx.x * blockDim.x + threadIdx.x;
  if (i < n4) {
    float4 v = ((const float4*)src)[i];
    bf16x4 o;
    o[0] = (__bf16)v.x; o[1] = (__bf16)v.y; o[2] = (__bf16)v.z; o[3] = (__bf16)v.w;
    ((bf16x4*)dst)[i] = o;
  }
}

__global__ void cvt_w4(const float* __restrict__ wq, const float* __restrict__ wk,
                       const float* __restrict__ wv, const float* __restrict__ wo,
                       __bf16* __restrict__ dst) {
  int i = blockIdx.x * 256 + threadIdx.x;
  int sel = i >> 18;
  const float* src = sel == 0 ? wq : sel == 1 ? wk : sel == 2 ? wv : wo;
  int j = i & 262143;
  float4 v = ((const float4*)src)[j];
  bf16x4 o;
  o[0] = (__bf16)v.x; o[1] = (__bf16)v.y; o[2] = (__bf16)v.z; o[3] = (__bf16)v.w;
  ((bf16x4*)dst)[i] = o;
}

// ------------------------------- RoPE table --------------------------------
__global__ void rope_table(float* __restrict__ ct, float* __restrict__ st) {
  int i = blockIdx.x * 256 + threadIdx.x;
  int pos = i >> 5, f = i & 31;
  float inv = powf(10000.0f, -(float)f * (1.0f / 32.0f));
  float a = (float)pos * inv;
  ct[i] = cosf(a);
  st[i] = sinf(a);
}

// --------------- phase-split GEMM: C = A(8192xK) * B(NxK)^T ----------------
// BM=256, BN=128, BK=64, 512 thr = 8 waves (4M x 2N), per-wave 64x64.
// Block map: XCD k owns bm in {4k..4k+3} (A panels pinned in its L2, 2MB),
// bn sweeps -> A fetched ~once per XCD, B streams.
// MODE 4: fused QKV (N=3072): seg 0=Q(RoPE+QSCALE) 1=K(RoPE) 2=V^T
// MODE 3: out f32 (N=1024)
template <int MODE>
__global__ __launch_bounds__(512, 2) void gemm8(const __bf16* __restrict__ A,
                                                const __bf16* __restrict__ Bw,
                                                void* __restrict__ Cout,
                                                const int* __restrict__ tpos,
                                                const float* __restrict__ ct,
                                                const float* __restrict__ st) {
  __shared__ __align__(16) char LB[98304];
  const int nk = 16;  // K=1024 / BK=64
  const int t = threadIdx.x, w = t >> 6, l = t & 63;
  const int lr = l & 15, lg = l >> 4;
  const int wr = w >> 1, wc = w & 1;
  // A-panel XCD-pinned map (round-robin id->XCD assumption, id&7 = xcd)
  const int id = blockIdx.x;
  const int xcd = id & 7, i = id >> 3;
  const int bm = xcd * 4 + (i & 3);  // 4 panels per XCD, L2-resident
  const int bn = i >> 2;             // sweeps 0..23 (MODE4) / 0..7 (MODE3)

  const int srow = t >> 3;
  const int scbs = ((t & 7) * 16) ^ ((srow & 7) << 4);
  const char* Ag = (const char*)A + (size_t)(bm * 256 + srow) * 2048 + scbs;
  const char* Bg = (const char*)Bw + (size_t)(bn * 128 + srow) * 2048 + scbs;
  char* lw = LB + w * 1024;  // wave-uniform dest base

#define STAGE_A(d, KT)                                                     \
  {                                                                        \
    GL16(Ag + (KT) * 128, lw + (d) * 32768);                               \
    GL16(Ag + (KT) * 128 + (size_t)64 * 2048, lw + (d) * 32768 + 8192);    \
    GL16(Ag + (KT) * 128 + (size_t)128 * 2048, lw + (d) * 32768 + 16384);  \
    GL16(Ag + (KT) * 128 + (size_t)192 * 2048, lw + (d) * 32768 + 24576);  \
  }
#define STAGE_B(d, KT)                                                     \
  {                                                                        \
    GL16(Bg + (KT) * 128, lw + 65536 + (d) * 16384);                       \
    GL16(Bg + (KT) * 128 + (size_t)64 * 2048, lw + 65536 + (d) * 16384 + 8192); \
  }

  const int sw = (lr & 7) << 4;
  const int c0 = (lg * 16) ^ sw;         // kk=0
  const int c1 = (64 + lg * 16) ^ sw;    // kk=1

  f32x4 acc[4][4] = {};

  STAGE_A(0, 0) STAGE_B(0, 0) STAGE_A(1, 1)
  asm volatile("s_waitcnt vmcnt(4)" ::: "memory");
  __builtin_amdgcn_s_barrier();
  __builtin_amdgcn_sched_barrier(0);

#define KTILE(KT, X)                                                          \
  {                                                                           \
    const char* Ab = LB + (X) * 32768;                                        \
    const char* Bb = LB + 65536 + (X) * 16384;                                \
    bf16x8 af[4][2], bf[2][2];                                                \
    _Pragma("unroll") for (int m = 0; m < 4; ++m) {                           \
      const int ar = (wr * 64 + m * 16 + lr) * 128;                           \
      af[m][0] = *(const bf16x8*)(Ab + ar + c0);                              \
      af[m][1] = *(const bf16x8*)(Ab + ar + c1);                              \
    }                                                                         \
    _Pragma("unroll") for (int n = 0; n < 2; ++n) {                           \
      const int br = (wc * 64 + n * 16 + lr) * 128;                           \
      bf[n][0] = *(const bf16x8*)(Bb + br + c0);                              \
      bf[n][1] = *(const bf16x8*)(Bb + br + c1);                              \
    }                                                                         \
    if ((KT) + 1 < nk) STAGE_B((X) ^ 1, (KT) + 1)                             \
    __builtin_amdgcn_s_barrier();                                             \
    __builtin_amdgcn_sched_barrier(0);                                        \
    __builtin_amdgcn_s_setprio(1);                                            \
    _Pragma("unroll") for (int m = 0; m < 4; ++m)                             \
      _Pragma("unroll") for (int kk = 0; kk < 2; ++kk) {                      \
        acc[m][0] = MFMA16(af[m][kk], bf[0][kk], acc[m][0]);                  \
        acc[m][1] = MFMA16(af[m][kk], bf[1][kk], acc[m][1]);                  \
      }                                                                       \
    __builtin_amdgcn_s_setprio(0);                                            \
    __builtin_amdgcn_s_barrier();                                             \
    __builtin_amdgcn_sched_barrier(0);                                        \
    _Pragma("unroll") for (int n = 0; n < 2; ++n) {                           \
      const int br = (wc * 64 + (n + 2) * 16 + lr) * 128;                     \
      bf[n][0] = *(const bf16x8*)(Bb + br + c0);                              \
      bf[n][1] = *(const bf16x8*)(Bb + br + c1);                              \
    }                                                                         \
    if ((KT) + 2 < nk) STAGE_A(X, (KT) + 2)                                   \
    __builtin_amdgcn_s_barrier();                                             \
    __builtin_amdgcn_sched_barrier(0);                                        \
    __builtin_amdgcn_s_setprio(1);                                            \
    _Pragma("unroll") for (int m = 0; m < 4; ++m)                             \
      _Pragma("unroll") for (int kk = 0; kk < 2; ++kk) {                      \
        acc[m][2] = MFMA16(af[m][kk], bf[0][kk], acc[m][2]);                  \
        acc[m][3] = MFMA16(af[m][kk], bf[1][kk], acc[m][3]);                  \
      }                                                                       \
    __builtin_amdgcn_s_setprio(0);                                            \
    if ((KT) + 2 < nk)                                                        \
      asm volatile("s_waitcnt vmcnt(4)" ::: "memory");                        \
    else                                                                      \
      asm volatile("s_waitcnt vmcnt(0)" ::: "memory");                        \
    __builtin_amdgcn_s_barrier();                                             \
    __builtin_amdgcn_sched_barrier(0);                                        \
  }

  for (int kt = 0; kt < nk; kt += 2) {
    KTILE(kt, 0)
    KTILE(kt + 1, 1)
  }

  // ---------------- epilogue ----------------
  if (MODE == 3) {
    float* outp = (float*)Cout;
#pragma unroll
    for (int m = 0; m < 4; ++m)
#pragma unroll
      for (int n = 0; n < 4; ++n)
#pragma unroll
        for (int e = 0; e < 4; ++e) {
          const int grow = bm * 256 + wr * 64 + m * 16 + lg * 4 + e;
          const int gcol = bn * 128 + wc * 64 + n * 16 + lr;
          outp[(size_t)grow * 1024 + gcol] = acc[m][n][e];
        }
  } else {
    const int seg = bn >> 3;  // 0=Q 1=K 2=V
    const int bnn = bn & 7;
    if (seg < 2) {
      const int h = bnn * 2 + wc;
      __bf16* base = (__bf16*)Cout + (size_t)seg * 8388608;
#pragma unroll
      for (int m = 0; m < 4; ++m)
#pragma unroll
        for (int e = 0; e < 4; ++e) {
          const int grow = bm * 256 + wr * 64 + m * 16 + lg * 4 + e;
          const int pos = tpos[grow];
          const int b = grow >> 11, s = grow & 2047;
          __bf16* orow = &base[(((size_t)(b * 16 + h)) * 2048 + s) * 64];
#pragma unroll
          for (int j = 0; j < 2; ++j) {
            const int dd = j * 16 + lr;
            const float c = ct[pos * 32 + dd], sn = st[pos * 32 + dd];
            float x1 = acc[m][j][e], x2 = acc[m][j + 2][e];
            float o1 = x1 * c - x2 * sn;
            float o2 = x2 * c + x1 * sn;
            if (seg == 0) { o1 *= QSCALE; o2 *= QSCALE; }
            orow[dd] = (__bf16)o1;
            orow[dd + 32] = (__bf16)o2;
          }
        }
    } else {
      __bf16* base = (__bf16*)Cout + 16777216;
#pragma unroll
      for (int m = 0; m < 4; ++m)
#pragma unroll
        for (int n = 0; n < 4; ++n) {
          const int grow0 = bm * 256 + wr * 64 + m * 16 + lg * 4;
          const int gcs = bnn * 128 + wc * 64 + n * 16 + lr;
          const int b = grow0 >> 11, s = grow0 & 2047;
          const int h = gcs >> 6, d = gcs & 63;
          bf16x4 vv;
#pragma unroll
          for (int e = 0; e < 4; ++e) vv[e] = (__bf16)acc[m][n][e];
          *(bf16x4*)&base[(((size_t)(b * 16 + h)) * 64 + d) * 2048 + s] = vv;
        }
    }
  }
}

// ------------------------- paired-causal flash attention -------------------
// 256 blocks x 1024 thr (16 warps x 32 q rows). Block = q-blocks {p,7-p};
// each warp owns ONE 32-row tile; SIMD w&3 hosts 2 light + 2 heavy waves ->
// 4 waves/SIMD, causal skew staggers VALU/MFMA phases across waves.
static __device__ __forceinline__ u32 pk2(float a, float b) {
  union { __bf16 h[2]; u32 w; } u;
  u.h[0] = (__bf16)a; u.h[1] = (__bf16)b;
  return u.w;
}

#define PACK_FRAG(SRC, OFF, OUT)                                            \
  {                                                                         \
    u32 c01 = pk2(SRC[(OFF) + 0], SRC[(OFF) + 1]);                          \
    u32 c23 = pk2(SRC[(OFF) + 2], SRC[(OFF) + 3]);                          \
    u32 c45 = pk2(SRC[(OFF) + 4], SRC[(OFF) + 5]);                          \
    u32 c67 = pk2(SRC[(OFF) + 6], SRC[(OFF) + 7]);                          \
    u32 x1_ = (u32)__shfl_xor((int)(hi ? c01 : c45), 32);                   \
    u32 x2_ = (u32)__shfl_xor((int)(hi ? c23 : c67), 32);                   \
    union { u32 w[4]; bf16x8 v; } fu_;                                      \
    fu_.w[0] = hi ? x1_ : c01;                                              \
    fu_.w[1] = hi ? x2_ : c23;                                              \
    fu_.w[2] = hi ? c45 : x1_;                                              \
    fu_.w[3] = hi ? c67 : x2_;                                              \
    OUT = fu_.v;                                                            \
  }

#define KOFF(row, cb) ((row) * 128 + ((cb) ^ (((row) & 7) << 4)))
#define VOFF(row, cb) ((row) * 256 + ((cb) ^ (((row) & 7) << 4)))

static __device__ __forceinline__ void qkt(const char* kcs, const bf16x8* qf,
                                           int lq, int hi, f32x16& s0, f32x16& s1) {
  s0 = (f32x16){}; s1 = (f32x16){};
#pragma unroll
  for (int ds = 0; ds < 4; ++ds) {
    bf16x8 kf = *(const bf16x8*)(kcs + KOFF(lq, ds * 32 + hi * 16));
    s0 = MFMA32(kf, qf[ds], s0);
  }
#pragma unroll
  for (int ds = 0; ds < 4; ++ds) {
    bf16x8 kf = *(const bf16x8*)(kcs + KOFF(32 + lq, ds * 32 + hi * 16));
    s1 = MFMA32(kf, qf[ds], s1);
  }
}

static __device__ __forceinline__ float maskmax(f32x16& s0, f32x16& s1, int k0,
                                                int q0w, int qrow, int hi) {
  if (k0 + 63 > q0w) {
#pragma unroll
    for (int r = 0; r < 16; ++r) {
      int kl_ = k0 + (r & 3) + 8 * (r >> 2) + 4 * hi;
      s0[r] = (kl_ > qrow) ? -1e30f : s0[r];
      s1[r] = (kl_ + 32 > qrow) ? -1e30f : s1[r];
    }
  }
  float m[8];
#pragma unroll
  for (int r = 0; r < 8; ++r)
    m[r] = fmaxf(fmaxf(s0[r], s0[r + 8]), fmaxf(s1[r], s1[r + 8]));
#pragma unroll
  for (int r = 0; r < 4; ++r) m[r] = fmaxf(m[r], m[r + 4]);
  float pm = fmaxf(fmaxf(m[0], m[1]), fmaxf(m[2], m[3]));
  return fmaxf(pm, __shfl_xor(pm, 32));
}

static __device__ __forceinline__ void smpack(f32x16& s0, f32x16& s1, float pmax,
                                              float& mrun, float& lrun,
                                              f32x16& o0, f32x16& o1,
                                              bf16x8* pa, int hi) {
  if (!__all(pmax <= mrun + 8.0f)) {
    float nm = fmaxf(mrun, pmax);
    float corr = EXP2(mrun - nm);
    mrun = nm;
    lrun *= corr;
#pragma unroll
    for (int r = 0; r < 16; ++r) { o0[r] *= corr; o1[r] *= corr; }
  }
  float rsp0 = 0.f, rsp1 = 0.f, rsp2 = 0.f, rsp3 = 0.f;
#pragma unroll
  for (int r = 0; r < 4; ++r) {
    float e0 = EXP2(s0[r] - mrun), e1 = EXP2(s0[r + 4] - mrun);
    float e2 = EXP2(s0[r + 8] - mrun), e3 = EXP2(s0[r + 12] - mrun);
    s0[r] = e0; s0[r + 4] = e1; s0[r + 8] = e2; s0[r + 12] = e3;
    rsp0 += e0; rsp1 += e1; rsp2 += e2; rsp3 += e3;
  }
#pragma unroll
  for (int r = 0; r < 4; ++r) {
    float e0 = EXP2(s1[r] - mrun), e1 = EXP2(s1[r + 4] - mrun);
    float e2 = EXP2(s1[r + 8] - mrun), e3 = EXP2(s1[r + 12] - mrun);
    s1[r] = e0; s1[r + 4] = e1; s1[r + 8] = e2; s1[r + 12] = e3;
    rsp0 += e0; rsp1 += e1; rsp2 += e2; rsp3 += e3;
  }
  float rs = (rsp0 + rsp1) + (rsp2 + rsp3);
  rs += __shfl_xor(rs, 32);
  lrun += rs;
  PACK_FRAG(s0, 0, pa[0])
  PACK_FRAG(s0, 8, pa[1])
  PACK_FRAG(s1, 0, pa[2])
  PACK_FRAG(s1, 8, pa[3])
}

static __device__ __forceinline__ void pv(const char* vc, int vcb0, int lq, int hi,
                                          const bf16x8* pa, f32x16& o0, f32x16& o1) {
#pragma unroll
  for (int fi = 0; fi < 4; ++fi) {
    bf16x8 vf = *(const bf16x8*)(vc + VOFF(lq, vcb0 + fi * 32 + hi * 16));
    o0 = MFMA32(vf, pa[fi], o0);
  }
#pragma unroll
  for (int fi = 0; fi < 4; ++fi) {
    bf16x8 vf = *(const bf16x8*)(vc + VOFF(32 + lq, vcb0 + fi * 32 + hi * 16));
    o1 = MFMA32(vf, pa[fi], o1);
  }
}

__global__ __launch_bounds__(1024) void attn_fwd(const __bf16* __restrict__ Q,
                                                 const __bf16* __restrict__ Kb,
                                                 const __bf16* __restrict__ VTg,
                                                 __bf16* __restrict__ O) {
  __shared__ __align__(16) __bf16 Ks[2][128 * 64];  // 16KB per buf
  __shared__ __align__(16) __bf16 Vs[2][64 * 128];  // 16KB per buf
  const int t = threadIdx.x, w = t >> 6, l = t & 63;
  const int lq = l & 31, hi = l >> 5;
  const int id = blockIdx.x;
  const int bh = (id & 7) + 8 * (id >> 5);  // same-head blocks share an XCD
  const int p = (id >> 3) & 3;
  // SIMD w&3 hosts waves {w, w+4, w+8, w+12} = 2 light + 2 heavy
  const int member = (w >> 2) & 1;
  const int ridx = (w & 3) | ((w >> 3) << 2);  // 0..7
  const int qb = member ? 7 - p : p;
  const int q0w = qb * 256 + ridx * 32;
  const int qrow = q0w + lq;
  const size_t kbaseB = (size_t)bh * (2048 * 64 * 2);
  const size_t vbaseB = (size_t)bh * (64 * 2048 * 2);

  // staging: 1024 thr x 16B = full 16KB tile per GL16
  const int srow = t >> 3;                               // 0..127 (K rows)
  const int scolb = ((t & 7) * 16) ^ ((srow & 7) << 4);  // inverse swizzle
  const int vrow = t >> 4;                               // 0..63 (V^T rows)
  const int vcolb = ((t & 15) * 16) ^ ((vrow & 7) << 4);
  const char* kgp = (const char*)Kb + kbaseB + (size_t)srow * 128 + scolb;
  const char* vgp = (const char*)VTg + vbaseB + (size_t)vrow * 4096 + vcolb;
  char* kl = (char*)&Ks[0][0] + w * 1024;  // wave-uniform dest
  char* vl = (char*)&Vs[0][0] + w * 1024;

#define STAGE(bi, KT)                                                      \
  {                                                                        \
    GL16(kgp + (size_t)(KT) * 16384, kl + (bi) * 16384);                   \
    GL16(vgp + (size_t)(KT) * 256, vl + (bi) * 16384);                     \
  }

  // Q B-fragments (RoPE + 0.125*log2e already folded in by GEMM epilogue)
  const size_t qbase = (size_t)bh * (2048 * 64);
  bf16x8 qf[4];
#pragma unroll
  for (int ds = 0; ds < 4; ++ds)
    qf[ds] = *(const bf16x8*)&Q[qbase + (size_t)qrow * 64 + ds * 16 + hi * 8];

  f32x16 o0 = {}, o1 = {};
  float mr = -1e30f, lsum = 0.0f;

  const int nkt = 2 * (7 - p) + 2;  // block-uniform (heavy member bound)
  STAGE(0, 0)
  int cur = 0;
  for (int kt = 0; kt < nkt; ++kt) {
    if (kt + 1 < nkt) {
      STAGE(cur ^ 1, kt + 1)
      asm volatile("s_waitcnt vmcnt(2)" ::: "memory");
    } else {
      asm volatile("s_waitcnt vmcnt(0)" ::: "memory");
    }
    __builtin_amdgcn_s_barrier();
    __builtin_amdgcn_sched_barrier(0);
    const char* kc = (const char*)&Ks[cur][0];
    const char* vc = (const char*)&Vs[cur][0];

#pragma unroll
    for (int sub = 0; sub < 2; ++sub) {
      const int k0 = kt * 128 + sub * 64;
      if (k0 <= q0w + 31) {  // warp-uniform causal skip
        const char* kcs = kc + sub * 8192;
        f32x16 s0, s1;
        __builtin_amdgcn_s_setprio(1);
        qkt(kcs, qf, lq, hi, s0, s1);
        __builtin_amdgcn_s_setprio(0);
        float pm = maskmax(s0, s1, k0, q0w, qrow, hi);
        bf16x8 pa[4];
        smpack(s0, s1, pm, mr, lsum, o0, o1, pa, hi);
        __builtin_amdgcn_s_setprio(1);
        pv(vc, sub * 128, lq, hi, pa, o0, o1);
        __builtin_amdgcn_s_setprio(0);
      }
    }
    __builtin_amdgcn_s_barrier();
    cur ^= 1;
  }

  // epilogue: O^T reg r -> d = dtile*32 + (r&3) + 8*(r>>2) + 4*hi, q = lane&31
  const int b = bh >> 4, h = bh & 15;
  float inv = 1.0f / lsum;
  __bf16* orow = O + ((size_t)(b * 2048 + qrow)) * 1024 + h * 64;
#pragma unroll
  for (int rq = 0; rq < 4; ++rq) {
    bf16x4 v0, v1;
#pragma unroll
    for (int e = 0; e < 4; ++e) {
      v0[e] = (__bf16)(o0[rq * 4 + e] * inv);
      v1[e] = (__bf16)(o1[rq * 4 + e] * inv);
    }
    *(bf16x4*)&orow[8 * rq + 4 * hi] = v0;
    *(bf16x4*)&orow[32 + 8 * rq + 4 * hi] = v1;
  }
}

// ---------------------------------------------------------------------------
extern "C" void kernel_launch(void* const* d_in, const int* in_sizes, int n_in,
                              void* d_out, int out_size, void* d_ws, size_t ws_size,
                              hipStream_t stream) {
  const float* x = (const float*)d_in[0];
  const float* wq = (const float*)d_in[1];
  const float* wk = (const float*)d_in[2];
  const float* wv = (const float*)d_in[3];
  const float* wo = (const float*)d_in[4];
  const int* tpos = (const int*)d_in[5];
  float* out = (float*)d_out;

  const size_t SZ_X = 8192u * 1024u * 2u;
  const size_t SZ_W = 1024u * 1024u * 2u;
  const size_t SZ_T = 2048u * 32u * 4u;
  const size_t NEED = SZ_X * 4 + SZ_W * 4 + SZ_T * 2;
  if (ws_size < NEED) return;

  char* p = (char*)d_ws;
  __bf16* xb  = (__bf16*)p; p += SZ_X;   // reused as attention output (AO)
  __bf16* wqb = (__bf16*)p; p += SZ_W;   // 4 weights contiguous (wq|wk|wv|wo)
  __bf16* wkb = (__bf16*)p; p += SZ_W;
  __bf16* wvb = (__bf16*)p; p += SZ_W;
  __bf16* wob = (__bf16*)p; p += SZ_W;
  __bf16* Qb  = (__bf16*)p; p += SZ_X;   // Q | K | V^T contiguous
  __bf16* Kbf = (__bf16*)p; p += SZ_X;
  __bf16* VTg = (__bf16*)p; p += SZ_X;
  float* ct = (float*)p; p += SZ_T;
  float* st = (float*)p; p += SZ_T;
  __bf16* AOb = xb;
  (void)wkb; (void)wvb;

  cvt_kernel<<<8192, 256, 0, stream>>>(x, xb, 2097152);
  cvt_w4<<<4096, 256, 0, stream>>>(wq, wk, wv, wo, wqb);
  rope_table<<<256, 256, 0, stream>>>(ct, st);

  // fused QKV: B = wq|wk|wv rows (contiguous), N=3072; grid 768 = 3/CU
  gemm8<4><<<768, 512, 0, stream>>>(xb, wqb, (void*)Qb, tpos, ct, st);

  attn_fwd<<<256, 1024, 0, stream>>>(Qb, Kbf, VTg, AOb);

  // out projection: N=1024; grid 256 = 1/CU
  gemm8<3><<<256, 512, 0, stream>>>(AOb, wob, (void*)out, tpos, ct, st);
}